// Round 3
// baseline (5617.759 us; speedup 1.0000x reference)
//
#include <hip/hip_runtime.h>
#include <cstdint>
#include <cstddef>

#define BB   256
#define DIM  384
#define NN   128
#define NH   4
#define NG   2
#define NKK  4
#define DHH  96
#define DG   192
#define KSZ  7
#define DFF  2048

static __device__ __forceinline__ float geluf(float x) {
  return 0.5f * x * (1.0f + erff(x * 0.70710678118654752440f));
}

// ---------------- LayerNorm over rows of length 384 -------------------------
__global__ __launch_bounds__(128) void ln_rows_kernel(
    const float* __restrict__ X,
    const float* __restrict__ gam, const float* __restrict__ bet,
    float* __restrict__ out)
{
  const int row = blockIdx.x;
  const int t = threadIdx.x;
  const size_t base = (size_t)row * DIM;
  float x0 = X[base + t], x1 = X[base + t + 128], x2 = X[base + t + 256];
  __shared__ float ws[2];
  float s = x0 + x1 + x2;
#pragma unroll
  for (int o = 32; o; o >>= 1) s += __shfl_down(s, o);
  if ((t & 63) == 0) ws[t >> 6] = s;
  __syncthreads();
  const float m = (ws[0] + ws[1]) * (1.0f / DIM);
  __syncthreads();
  const float d0 = x0 - m, d1 = x1 - m, d2 = x2 - m;
  float v = d0 * d0 + d1 * d1 + d2 * d2;
#pragma unroll
  for (int o = 32; o; o >>= 1) v += __shfl_down(v, o);
  if ((t & 63) == 0) ws[t >> 6] = v;
  __syncthreads();
  const float var = (ws[0] + ws[1]) * (1.0f / DIM);
  const float rs = rsqrtf(var + 1e-5f);
  out[base + t]       = d0 * rs * gam[t]       + bet[t];
  out[base + t + 128] = d1 * rs * gam[t + 128] + bet[t + 128];
  out[base + t + 256] = d2 * rs * gam[t + 256] + bet[t + 256];
}

// ---------------- (B,DIM,N) + pe(N,DIM) -> rows (B,N,DIM) --------------------
__global__ __launch_bounds__(256) void transpose_addpe(
    const float* __restrict__ X, const float* __restrict__ pe,
    float* __restrict__ out)
{
  __shared__ float tile[32][33];
  const int b = blockIdx.z;
  const int n0 = blockIdx.x * 32, d0 = blockIdx.y * 32;
  const int tx = threadIdx.x, ty = threadIdx.y;   // 32 x 8
#pragma unroll
  for (int i = 0; i < 4; i++) {
    const int d = d0 + ty + i * 8;
    tile[ty + i * 8][tx] = X[(size_t)b * DIM * NN + (size_t)d * NN + n0 + tx];
  }
  __syncthreads();
#pragma unroll
  for (int i = 0; i < 4; i++) {
    const int n = n0 + ty + i * 8;
    const int d = d0 + tx;
    out[((size_t)b * NN + n) * DIM + d] = tile[tx][ty + i * 8] + pe[n * DIM + d];
  }
}

// ---------------- rows (B,N,DIM) -> (B,DIM,N) -------------------------------
__global__ __launch_bounds__(256) void transpose_to_cf(
    const float* __restrict__ rows, float* __restrict__ out)
{
  __shared__ float tile[32][33];
  const int b = blockIdx.z;
  const int n0 = blockIdx.x * 32, d0 = blockIdx.y * 32;
  const int tx = threadIdx.x, ty = threadIdx.y;
#pragma unroll
  for (int i = 0; i < 4; i++) {
    const int n = n0 + ty + i * 8;
    tile[ty + i * 8][tx] = rows[((size_t)b * NN + n) * DIM + d0 + tx];
  }
  __syncthreads();
#pragma unroll
  for (int i = 0; i < 4; i++) {
    const int d = d0 + ty + i * 8;
    out[(size_t)b * DIM * NN + (size_t)d * NN + n0 + tx] = tile[tx][ty + i * 8];
  }
}

// ---------------- generic fp32 GEMM: C = act(A@W + bias) (+resid) -----------
// A (M,K) rm, W (K,Nc) rm, C (M,Nc) rm. M%128==0, Nc%128==0, K%16==0.
// Grid: (Nc/128, M/128). Pointers may be pre-offset (chunk-local).
template<bool RELU, bool RES>
__global__ __launch_bounds__(256) void gemm_kernel(
    const float* __restrict__ A, const float* __restrict__ W,
    const float* __restrict__ bias, const float* __restrict__ resid,
    float* __restrict__ C, int K, int Nc)
{
  __shared__ __align__(16) float As[16][128];
  __shared__ __align__(16) float Bs[16][128];
  const int tid = threadIdx.x;
  const int tx = tid & 15, ty = tid >> 4;
  const int bx = blockIdx.x, by = blockIdx.y;
  const size_t rowBase = (size_t)by * 128;
  const int colBase = bx * 128;
  float acc[8][8] = {};
  for (int k0 = 0; k0 < K; k0 += 16) {
#pragma unroll
    for (int l = 0; l < 2; l++) {
      const int f4 = tid + l * 256;
      const int r = f4 >> 2;
      const int c4 = (f4 & 3) * 4;
      const float4 av = *reinterpret_cast<const float4*>(
          &A[(rowBase + r) * (size_t)K + k0 + c4]);
      As[c4 + 0][r] = av.x; As[c4 + 1][r] = av.y;
      As[c4 + 2][r] = av.z; As[c4 + 3][r] = av.w;
    }
#pragma unroll
    for (int l = 0; l < 2; l++) {
      const int f4 = tid + l * 256;
      const int kr = f4 >> 5;
      const int n4 = (f4 & 31) * 4;
      *reinterpret_cast<float4*>(&Bs[kr][n4]) =
          *reinterpret_cast<const float4*>(&W[(size_t)(k0 + kr) * Nc + colBase + n4]);
    }
    __syncthreads();
#pragma unroll
    for (int kk = 0; kk < 16; kk++) {
      float a[8], bb[8];
      *(float4*)&a[0]  = *(float4*)&As[kk][ty * 8];
      *(float4*)&a[4]  = *(float4*)&As[kk][ty * 8 + 4];
      *(float4*)&bb[0] = *(float4*)&Bs[kk][tx * 8];
      *(float4*)&bb[4] = *(float4*)&Bs[kk][tx * 8 + 4];
#pragma unroll
      for (int i = 0; i < 8; i++)
#pragma unroll
        for (int j = 0; j < 8; j++)
          acc[i][j] = fmaf(a[i], bb[j], acc[i][j]);
    }
    __syncthreads();
  }
  float bv[8];
#pragma unroll
  for (int j = 0; j < 8; j++) bv[j] = bias[colBase + tx * 8 + j];
#pragma unroll
  for (int i = 0; i < 8; i++) {
    const size_t row = rowBase + ty * 8 + i;
    float o[8];
#pragma unroll
    for (int j = 0; j < 8; j++) {
      float v = acc[i][j] + bv[j];
      if (RELU) v = fmaxf(v, 0.0f);
      o[j] = v;
    }
    if (RES) {
#pragma unroll
      for (int j = 0; j < 8; j++)
        o[j] += resid[row * Nc + colBase + tx * 8 + j];
    }
    *(float4*)&C[row * Nc + colBase + tx * 8]     = *(float4*)&o[0];
    *(float4*)&C[row * Nc + colBase + tx * 8 + 4] = *(float4*)&o[4];
  }
}

// ------- GEMM with bilinear-sampled A (fused grid_sample), layer-1 k/v ------
// Global by-unit = byBase + blockIdx.y encodes (b, kk); tile rows are n=0..127.
// A[(b,kk,n)][d] = lerp(kvrows[b, y0, d], kvrows[b, y0+1, d]); C written at
// CHUNK-LOCAL rows (blockIdx.y*128 + n).
template<bool RELU>
__global__ __launch_bounds__(256) void gemm_sampled_kernel(
    const float* __restrict__ kvrows, const int* __restrict__ y0buf,
    const float* __restrict__ wbuf, const float* __restrict__ W,
    const float* __restrict__ bias, float* __restrict__ C,
    int K, int Nc, int byBase)
{
  __shared__ __align__(16) float As[16][128];
  __shared__ __align__(16) float Bs[16][128];
  const int tid = threadIdx.x;
  const int tx = tid & 15, ty = tid >> 4;
  const int bx = blockIdx.x;
  const int byG = blockIdx.y + byBase;        // global (b,kk) unit
  const int b = byG >> 2, kk = byG & 3;
  const size_t rowBase = (size_t)blockIdx.y * 128;  // chunk-local output row
  const int colBase = bx * 128;
  float acc[8][8] = {};
  for (int k0 = 0; k0 < K; k0 += 16) {
#pragma unroll
    for (int l = 0; l < 2; l++) {
      const int f4 = tid + l * 256;
      const int r = f4 >> 2;                 // = n
      const int c4 = (f4 & 3) * 4;
      const int d = k0 + c4;                 // same g across the float4
      const int g = d / DG;
      const int sidx = (((b * NG + g) * NKK) + kk) * NN + r;
      const int y0 = y0buf[sidx];
      const float w = wbuf[sidx];
      float4 v0 = make_float4(0.f, 0.f, 0.f, 0.f);
      float4 v1 = make_float4(0.f, 0.f, 0.f, 0.f);
      if (y0 >= 0)
        v0 = *reinterpret_cast<const float4*>(
            &kvrows[((size_t)b * NN + y0) * DIM + d]);
      if (y0 < NN - 1)
        v1 = *reinterpret_cast<const float4*>(
            &kvrows[((size_t)b * NN + y0 + 1) * DIM + d]);
      const float w0 = 1.0f - w;
      As[c4 + 0][r] = v0.x * w0 + v1.x * w;
      As[c4 + 1][r] = v0.y * w0 + v1.y * w;
      As[c4 + 2][r] = v0.z * w0 + v1.z * w;
      As[c4 + 3][r] = v0.w * w0 + v1.w * w;
    }
#pragma unroll
    for (int l = 0; l < 2; l++) {
      const int f4 = tid + l * 256;
      const int kr = f4 >> 5;
      const int n4 = (f4 & 31) * 4;
      *reinterpret_cast<float4*>(&Bs[kr][n4]) =
          *reinterpret_cast<const float4*>(&W[(size_t)(k0 + kr) * Nc + colBase + n4]);
    }
    __syncthreads();
#pragma unroll
    for (int kkk = 0; kkk < 16; kkk++) {
      float a[8], bb[8];
      *(float4*)&a[0]  = *(float4*)&As[kkk][ty * 8];
      *(float4*)&a[4]  = *(float4*)&As[kkk][ty * 8 + 4];
      *(float4*)&bb[0] = *(float4*)&Bs[kkk][tx * 8];
      *(float4*)&bb[4] = *(float4*)&Bs[kkk][tx * 8 + 4];
#pragma unroll
      for (int i = 0; i < 8; i++)
#pragma unroll
        for (int j = 0; j < 8; j++)
          acc[i][j] = fmaf(a[i], bb[j], acc[i][j]);
    }
    __syncthreads();
  }
  float bv[8];
#pragma unroll
  for (int j = 0; j < 8; j++) bv[j] = bias[colBase + tx * 8 + j];
#pragma unroll
  for (int i = 0; i < 8; i++) {
    const size_t row = rowBase + ty * 8 + i;
    float o[8];
#pragma unroll
    for (int j = 0; j < 8; j++) {
      float v = acc[i][j] + bv[j];
      if (RELU) v = fmaxf(v, 0.0f);
      o[j] = v;
    }
    *(float4*)&C[row * Nc + colBase + tx * 8]     = *(float4*)&o[0];
    *(float4*)&C[row * Nc + colBase + tx * 8 + 4] = *(float4*)&o[4];
  }
}

// ------- offsets: depthwise conv7 -> gelu -> pointwise -> tanh*4 -> coords --
__global__ __launch_bounds__(256) void offset_kernel(
    const float* __restrict__ qproj, const float* __restrict__ dw_w,
    const float* __restrict__ dw_b, const float* __restrict__ pw_w,
    int* __restrict__ y0buf, float* __restrict__ wbuf)
{
  const int gid = blockIdx.x * 256 + threadIdx.x;  // < B*G*N
  const int n = gid & (NN - 1);
  const int bg = gid >> 7;
  const int b = bg >> 1, g = bg & 1;
  const size_t qb = (size_t)b * NN * DIM + g * DG;
  float acc0 = 0.f, acc1 = 0.f, acc2 = 0.f, acc3 = 0.f;
  for (int c = 0; c < DG; ++c) {
    float wsum = dw_b[c];
#pragma unroll
    for (int tap = 0; tap < KSZ; ++tap) {
      const int np = n - 3 + tap;
      if ((unsigned)np < (unsigned)NN)
        wsum += qproj[qb + (size_t)np * DIM + c] * dw_w[c * KSZ + tap];
    }
    const float gl = geluf(wsum);
    acc0 += pw_w[0 * DG + c] * gl;
    acc1 += pw_w[1 * DG + c] * gl;
    acc2 += pw_w[2 * DG + c] * gl;
    acc3 += pw_w[3 * DG + c] * gl;
  }
  const float accs[4] = {acc0, acc1, acc2, acc3};
#pragma unroll
  for (int kk = 0; kk < NKK; ++kk) {
    const float off = tanhf(accs[kk]) * 4.0f;
    const float vgrid = (float)n + off;
    float vg = 2.0f * vgrid / (float)(NN - 1) - 1.0f;
    vg = fminf(fmaxf(vg, -1.0f), 1.0f);
    const float iy = ((vg + 1.0f) * (float)NN - 1.0f) * 0.5f;
    const float y0f = floorf(iy);
    const int idx = (bg * NKK + kk) * NN + n;
    y0buf[idx] = (int)y0f;
    wbuf[idx] = iy - y0f;
  }
}

// ------- per-position 4-key attention; adds result into qrows (residual) ----
// k_ch / v_ch are CHUNK-LOCAL (32 batches); qproj/qrows use global batch.
__global__ __launch_bounds__(128) void attn_kernel(
    const float* __restrict__ qproj, const float* __restrict__ k_ch,
    const float* __restrict__ v_ch, const float* __restrict__ attn_scale,
    float* __restrict__ qrows, int bBase)
{
  const int bid = blockIdx.x;                 // < 32*128*4
  const int h = bid & 3;
  const int bnl = bid >> 2;                   // local b*N + n
  const int bl = bnl >> 7;
  const int n = bnl & 127;
  const size_t bn = ((size_t)(bBase + bl)) * NN + n;   // global row
  const int t = threadIdx.x;
  const int lane = t & 63, wid = t >> 6;
  __shared__ float red[2][4];
  __shared__ float simsh[4];
  float qv = 0.f;
  if (t < DHH)
    qv = qproj[bn * DIM + h * DHH + t] * 0.10206207261596577f;  // 96^-0.5
#pragma unroll
  for (int kk = 0; kk < NKK; kk++) {
    float pv = 0.f;
    if (t < DHH)
      pv = qv * k_ch[(((size_t)bl * NKK + kk) * NN + n) * DIM + h * DHH + t];
#pragma unroll
    for (int o = 32; o; o >>= 1) pv += __shfl_down(pv, o);
    if (lane == 0) red[wid][kk] = pv;
  }
  __syncthreads();
  if (t == 0) {
#pragma unroll
    for (int kk = 0; kk < NKK; kk++)
      simsh[kk] = (red[0][kk] + red[1][kk]) * 0.08838834764831845f; // 128^-0.5
  }
  __syncthreads();
  const float s0 = simsh[0], s1 = simsh[1], s2 = simsh[2], s3 = simsh[3];
  const float m = fmaxf(fmaxf(s0, s1), fmaxf(s2, s3));
  const float sc = attn_scale[0];
  const float e0 = expf((s0 - m) * sc), e1 = expf((s1 - m) * sc);
  const float e2 = expf((s2 - m) * sc), e3 = expf((s3 - m) * sc);
  const float inv = 1.0f / (e0 + e1 + e2 + e3);
  if (t < DHH) {
    const size_t vb = ((size_t)bl * NKK * NN + n) * DIM + h * DHH + t;
    const size_t stride = (size_t)NN * DIM;
    float o = e0 * inv * v_ch[vb];
    o += e1 * inv * v_ch[vb + stride];
    o += e2 * inv * v_ch[vb + 2 * stride];
    o += e3 * inv * v_ch[vb + 3 * stride];
    const size_t oi = bn * DIM + h * DHH + t;
    qrows[oi] = qrows[oi] + o;      // fused residual: q_pe + attn_out
  }
}

extern "C" void kernel_launch(void* const* d_in, const int* in_sizes, int n_in,
                              void* d_out, int out_size, void* d_ws, size_t ws_size,
                              hipStream_t stream)
{
  const float* q_raw    = (const float*)d_in[0];
  const float* kv_raw   = (const float*)d_in[1];
  const float* emb_q    = (const float*)d_in[2];
  const float* ln_pq_g  = (const float*)d_in[3];
  const float* ln_pq_b  = (const float*)d_in[4];
  const float* emb_kv   = (const float*)d_in[5];
  const float* ln_pkv_g = (const float*)d_in[6];
  const float* ln_pkv_b = (const float*)d_in[7];
  const float* Wq1 = (const float*)d_in[8];   const float* bq1 = (const float*)d_in[9];
  const float* Wq2 = (const float*)d_in[10];  const float* bq2 = (const float*)d_in[11];
  const float* Wk1 = (const float*)d_in[12];  const float* bk1 = (const float*)d_in[13];
  const float* Wk2 = (const float*)d_in[14];  const float* bk2 = (const float*)d_in[15];
  const float* Wv1 = (const float*)d_in[16];  const float* bv1 = (const float*)d_in[17];
  const float* Wv2 = (const float*)d_in[18];  const float* bv2 = (const float*)d_in[19];
  const float* dw_w = (const float*)d_in[20]; const float* dw_b = (const float*)d_in[21];
  const float* pw_w = (const float*)d_in[22];
  const float* ln1_g = (const float*)d_in[23]; const float* ln1_b = (const float*)d_in[24];
  const float* ln2_g = (const float*)d_in[25]; const float* ln2_b = (const float*)d_in[26];
  const float* Wf1 = (const float*)d_in[27];  const float* bf1 = (const float*)d_in[28];
  const float* Wf2 = (const float*)d_in[29];  const float* bf2 = (const float*)d_in[30];
  const float* attn_scale = (const float*)d_in[31];
  float* out = (float*)d_out;

  // ---- workspace layout (floats); peak ≈ 219 MiB ----
  // S = one (B,N,DIM) buffer = 12,582,912 floats (48 MiB).
  // [0,S)      qrows : q_pe rows; attn adds in-place; later lnout
  // [S,2S)     kvr   : kv_pe rows; later res (ln1 out)
  // [2S,3S)    qproj : q MLP out; later res2
  // [3S,4.5S)  chunk region: hid[S/2] | k_ch[S/2] | v_ch[S/2]
  //            (also hosts q-hidden scr [S] and FFN hidden quarter [1.33S])
  // [4.5S,..)  peq, pekv, y0buf, wbuf  (~2.5 MB)
  float* wsf = (float*)d_ws;
  const size_t S = (size_t)BB * NN * DIM;           // 12,582,912
  const size_t SH = S / 2;                          // chunk buffer size
  float* qrows = wsf;
  float* kvr   = qrows + S;
  float* qproj = kvr + S;
  float* hid   = qproj + S;          // chunk layer-1 out (16384 x 384)
  float* k_ch  = hid + SH;
  float* v_ch  = k_ch + SH;
  float* peq   = v_ch + SH;
  float* pekv  = peq + (size_t)NN * DIM;
  int*   y0buf = (int*)(pekv + (size_t)NN * DIM);
  float* wbuf  = (float*)(y0buf + (size_t)BB * NG * NKK * NN);
  float* scr   = hid;     // q-MLP hidden (S floats, spans hid..v_ch) pre-chunks
  float* res   = kvr;     // ln1 output (kvr dead after last sampled GEMM)
  float* ffnh  = hid;     // FFN hidden quarter (1.33S, spans chunk region)
  float* res2  = qproj;   // FFN output (+resid); qproj dead after last attn
  float* lnout = qrows;   // final LN out; qrows dead after ln1

  const int MQ = BB * NN;                      // 32768 q rows
  const int NCH = 8;                           // k/v batch-chunks (32 b each)
  const int B_PER_CH = BB / NCH;               // 32
  const int BY_PER_CH = B_PER_CH * NKK;        // 128 by-units per chunk
  const int ROWS_PER_CH = BY_PER_CH * NN;      // 16384 rows per chunk
  const int NFQ = 4;                           // FFN row-quarters
  const int FROWS = MQ / NFQ;                  // 8192

  // 1) positional-encoding LayerNorms (emb rows: N=128 x DIM)
  ln_rows_kernel<<<dim3(NN), dim3(128), 0, stream>>>(emb_q, ln_pq_g, ln_pq_b, peq);
  ln_rows_kernel<<<dim3(NN), dim3(128), 0, stream>>>(emb_kv, ln_pkv_g, ln_pkv_b, pekv);

  // 2) transpose to rows + add pos-enc
  transpose_addpe<<<dim3(NN / 32, DIM / 32, BB), dim3(32, 8), 0, stream>>>(
      q_raw, peq, qrows);
  transpose_addpe<<<dim3(NN / 32, DIM / 32, BB), dim3(32, 8), 0, stream>>>(
      kv_raw, pekv, kvr);

  // 3) q MLP (hidden in scr = chunk region, dead before chunks start)
  gemm_kernel<true, false><<<dim3(DIM / 128, MQ / 128), 256, 0, stream>>>(
      qrows, Wq1, bq1, nullptr, scr, DIM, DIM);
  gemm_kernel<false, false><<<dim3(DIM / 128, MQ / 128), 256, 0, stream>>>(
      scr, Wq2, bq2, nullptr, qproj, DIM, DIM);

  // 4) offset prediction -> sampling coords
  offset_kernel<<<dim3(BB * NG * NN / 256), 256, 0, stream>>>(
      qproj, dw_w, dw_b, pw_w, y0buf, wbuf);

  // 5) per batch-chunk: k MLP, v MLP (layer-1 fuses grid-sample), attention
  for (int c = 0; c < NCH; ++c) {
    const int byBase = c * BY_PER_CH;
    gemm_sampled_kernel<true><<<dim3(DIM / 128, BY_PER_CH), 256, 0, stream>>>(
        kvr, y0buf, wbuf, Wk1, bk1, hid, DIM, DIM, byBase);
    gemm_kernel<false, false><<<dim3(DIM / 128, ROWS_PER_CH / 128), 256, 0, stream>>>(
        hid, Wk2, bk2, nullptr, k_ch, DIM, DIM);
    gemm_sampled_kernel<true><<<dim3(DIM / 128, BY_PER_CH), 256, 0, stream>>>(
        kvr, y0buf, wbuf, Wv1, bv1, hid, DIM, DIM, byBase);
    gemm_kernel<false, false><<<dim3(DIM / 128, ROWS_PER_CH / 128), 256, 0, stream>>>(
        hid, Wv2, bv2, nullptr, v_ch, DIM, DIM);
    attn_kernel<<<dim3(B_PER_CH * NN * NH), 128, 0, stream>>>(
        qproj, k_ch, v_ch, attn_scale, qrows, c * B_PER_CH);
  }

  // 6) res = LN(q_pe + attn_out)  [qrows holds the fused sum]
  ln_rows_kernel<<<dim3(MQ), dim3(128), 0, stream>>>(qrows, ln1_g, ln1_b, res);

  // 7) FFN in row-quarters, residual fused into second GEMM
  for (int q = 0; q < NFQ; ++q) {
    const float* rq = res + (size_t)q * FROWS * DIM;
    gemm_kernel<true, false><<<dim3(DFF / 128, FROWS / 128), 256, 0, stream>>>(
        rq, Wf1, bf1, nullptr, ffnh, DIM, DFF);
    gemm_kernel<false, true><<<dim3(DIM / 128, FROWS / 128), 256, 0, stream>>>(
        ffnh, Wf2, bf2, rq, res2 + (size_t)q * FROWS * DIM, DFF, DIM);
  }

  // 8) final LN + transpose back to (B, DIM, N)
  ln_rows_kernel<<<dim3(MQ), dim3(128), 0, stream>>>(res2, ln2_g, ln2_b, lnout);
  transpose_to_cf<<<dim3(NN / 32, DIM / 32, BB), dim3(32, 8), 0, stream>>>(
      lnout, out);
}

// Round 7
// 1591.421 us; speedup vs baseline: 3.5300x; 3.5300x over previous
//
#include <hip/hip_runtime.h>
#include <hip/hip_bf16.h>
#include <cstdint>
#include <cstddef>

#define BB   256
#define DIM  384
#define NN   128
#define NH   4
#define NG   2
#define NKK  4
#define DHH  96
#define DG   192
#define KSZ  7
#define DFF  2048

typedef __attribute__((ext_vector_type(8))) short bf8_t;   // 8 bf16 (4 VGPR)
typedef __attribute__((ext_vector_type(4))) float f4_t;    // 4 f32 acc

static __device__ __forceinline__ float geluf(float x) {
  return 0.5f * x * (1.0f + erff(x * 0.70710678118654752440f));
}
static __device__ __forceinline__ short f2bf(float f) {
  union { __hip_bfloat16 h; short s; } u;
  u.h = __float2bfloat16(f);
  return u.s;
}

// ---------------- LayerNorm rows of 384; optional secondary bf16 output -----
template<bool WB>
__global__ __launch_bounds__(128) void ln_rows_kernel(
    const float* __restrict__ X,
    const float* __restrict__ gam, const float* __restrict__ bet,
    float* __restrict__ out, __hip_bfloat16* __restrict__ out2)
{
  const int row = blockIdx.x;
  const int t = threadIdx.x;
  const size_t base = (size_t)row * DIM;
  float x0 = X[base + t], x1 = X[base + t + 128], x2 = X[base + t + 256];
  __shared__ float ws[2];
  float s = x0 + x1 + x2;
#pragma unroll
  for (int o = 32; o; o >>= 1) s += __shfl_down(s, o);
  if ((t & 63) == 0) ws[t >> 6] = s;
  __syncthreads();
  const float m = (ws[0] + ws[1]) * (1.0f / DIM);
  __syncthreads();
  const float d0 = x0 - m, d1 = x1 - m, d2 = x2 - m;
  float v = d0 * d0 + d1 * d1 + d2 * d2;
#pragma unroll
  for (int o = 32; o; o >>= 1) v += __shfl_down(v, o);
  if ((t & 63) == 0) ws[t >> 6] = v;
  __syncthreads();
  const float var = (ws[0] + ws[1]) * (1.0f / DIM);
  const float rs = rsqrtf(var + 1e-5f);
  const float o0 = d0 * rs * gam[t]       + bet[t];
  const float o1 = d1 * rs * gam[t + 128] + bet[t + 128];
  const float o2 = d2 * rs * gam[t + 256] + bet[t + 256];
  out[base + t] = o0; out[base + t + 128] = o1; out[base + t + 256] = o2;
  if (WB) {
    out2[base + t]       = __float2bfloat16(o0);
    out2[base + t + 128] = __float2bfloat16(o1);
    out2[base + t + 256] = __float2bfloat16(o2);
  }
}

// ---------------- (B,DIM,N) + pe(N,DIM) -> rows (B,N,DIM) (+bf16 copy) ------
template<bool WB>
__global__ __launch_bounds__(256) void transpose_addpe(
    const float* __restrict__ X, const float* __restrict__ pe,
    float* __restrict__ out, __hip_bfloat16* __restrict__ outb)
{
  __shared__ float tile[32][33];
  const int b = blockIdx.z;
  const int n0 = blockIdx.x * 32, d0 = blockIdx.y * 32;
  const int tx = threadIdx.x, ty = threadIdx.y;   // 32 x 8
#pragma unroll
  for (int i = 0; i < 4; i++) {
    const int d = d0 + ty + i * 8;
    tile[ty + i * 8][tx] = X[(size_t)b * DIM * NN + (size_t)d * NN + n0 + tx];
  }
  __syncthreads();
#pragma unroll
  for (int i = 0; i < 4; i++) {
    const int n = n0 + ty + i * 8;
    const int d = d0 + tx;
    const float v = tile[tx][ty + i * 8] + pe[n * DIM + d];
    out[((size_t)b * NN + n) * DIM + d] = v;
    if (WB) outb[((size_t)b * NN + n) * DIM + d] = __float2bfloat16(v);
  }
}

// ---------------- rows (B,N,DIM) -> (B,DIM,N) -------------------------------
__global__ __launch_bounds__(256) void transpose_to_cf(
    const float* __restrict__ rows, float* __restrict__ out)
{
  __shared__ float tile[32][33];
  const int b = blockIdx.z;
  const int n0 = blockIdx.x * 32, d0 = blockIdx.y * 32;
  const int tx = threadIdx.x, ty = threadIdx.y;
#pragma unroll
  for (int i = 0; i < 4; i++) {
    const int n = n0 + ty + i * 8;
    tile[ty + i * 8][tx] = rows[((size_t)b * NN + n) * DIM + d0 + tx];
  }
  __syncthreads();
#pragma unroll
  for (int i = 0; i < 4; i++) {
    const int d = d0 + ty + i * 8;
    out[(size_t)b * DIM * NN + (size_t)d * NN + n0 + tx] = tile[tx][ty + i * 8];
  }
}

// ---------------- W (K,N) f32 -> WT (N,K) bf16 ------------------------------
__global__ __launch_bounds__(256) void wtrans_kernel(
    const float* __restrict__ W, __hip_bfloat16* __restrict__ WT, int K, int N)
{
  __shared__ float tile[32][33];
  const int n0 = blockIdx.x * 32, k0 = blockIdx.y * 32;
  const int tx = threadIdx.x, ty = threadIdx.y;   // 32 x 8
#pragma unroll
  for (int i = 0; i < 4; i++)
    tile[ty + i * 8][tx] = W[(size_t)(k0 + ty + i * 8) * N + n0 + tx];
  __syncthreads();
#pragma unroll
  for (int i = 0; i < 4; i++)
    WT[(size_t)(n0 + ty + i * 8) * K + k0 + tx] =
        __float2bfloat16(tile[tx][ty + i * 8]);
}

// ---------------- MFMA GEMM: C = act(A @ BT^T + bias) (+resid) --------------
// A [M][K] bf16 rm, BT [N][K] bf16 rm, bias f32. 256 thr = 4 waves (2x2),
// 128x128 tile, BK=32, 16x16x32 MFMA. K%32==0, M%128==0, N%128==0.
#define LDP 40   // LDS row pitch in bf16 (pad 32 -> 40, conflict-free)
template<bool RELU, bool RES, bool OUTBF>
__global__ __launch_bounds__(256) void mfma_gemm_kernel(
    const __hip_bfloat16* __restrict__ A, const __hip_bfloat16* __restrict__ BT,
    const float* __restrict__ bias, const float* __restrict__ resid,
    float* __restrict__ outf, __hip_bfloat16* __restrict__ outb,
    int K, int Nc)
{
  __shared__ __align__(16) short As[128 * LDP];
  __shared__ __align__(16) short Bs[128 * LDP];
  const int tid = threadIdx.x;
  const int lane = tid & 63, wid = tid >> 6;
  const int wm = wid >> 1, wn = wid & 1;
  const size_t rowBase = (size_t)blockIdx.y * 128;
  const size_t colBase = (size_t)blockIdx.x * 128;
  f4_t acc[4][4] = {};
  const int lr = lane & 15, lg = lane >> 4;     // frag row/col, k-group
  for (int k0 = 0; k0 < K; k0 += 32) {
#pragma unroll
    for (int l = 0; l < 2; l++) {
      const int c = tid + l * 256;
      const int r = c >> 2, ko = (c & 3) * 8;
      *(uint4*)&As[r * LDP + ko] =
          *(const uint4*)&A[(rowBase + r) * (size_t)K + k0 + ko];
      *(uint4*)&Bs[r * LDP + ko] =
          *(const uint4*)&BT[(colBase + r) * (size_t)K + k0 + ko];
    }
    __syncthreads();
    bf8_t af[4], bfr[4];
#pragma unroll
    for (int mi = 0; mi < 4; mi++)
      af[mi] = *(const bf8_t*)&As[(wm * 64 + mi * 16 + lr) * LDP + lg * 8];
#pragma unroll
    for (int ni = 0; ni < 4; ni++)
      bfr[ni] = *(const bf8_t*)&Bs[(wn * 64 + ni * 16 + lr) * LDP + lg * 8];
#pragma unroll
    for (int mi = 0; mi < 4; mi++)
#pragma unroll
      for (int ni = 0; ni < 4; ni++)
        acc[mi][ni] = __builtin_amdgcn_mfma_f32_16x16x32_bf16(
            af[mi], bfr[ni], acc[mi][ni], 0, 0, 0);
    __syncthreads();
  }
#pragma unroll
  for (int ni = 0; ni < 4; ni++) {
    const size_t col = colBase + wn * 64 + ni * 16 + lr;
    const float bv = bias[col];
#pragma unroll
    for (int mi = 0; mi < 4; mi++) {
#pragma unroll
      for (int r = 0; r < 4; r++) {
        const size_t row = rowBase + wm * 64 + mi * 16 + lg * 4 + r;
        float v = acc[mi][ni][r] + bv;
        if (RELU) v = fmaxf(v, 0.0f);
        if (RES) v += resid[row * Nc + col];
        if (OUTBF) outb[row * Nc + col] = __float2bfloat16(v);
        else       outf[row * Nc + col] = v;
      }
    }
  }
}

// ------- MFMA GEMM w/ bilinear-sampled A (fused grid_sample), k/v layer-1 ---
// by-unit = byBase+blockIdx.y encodes (b,kk); tile rows are n=0..127.
__global__ __launch_bounds__(256) void mfma_gemm_sampled_kernel(
    const float* __restrict__ kvrows, const int* __restrict__ y0buf,
    const float* __restrict__ wbuf, const __hip_bfloat16* __restrict__ BT,
    const float* __restrict__ bias, __hip_bfloat16* __restrict__ outb,
    int K, int Nc, int byBase)
{
  __shared__ __align__(16) short As[128 * LDP];
  __shared__ __align__(16) short Bs[128 * LDP];
  const int tid = threadIdx.x;
  const int lane = tid & 63, wid = tid >> 6;
  const int wm = wid >> 1, wn = wid & 1;
  const int byG = blockIdx.y + byBase;
  const int b = byG >> 2, kk = byG & 3;
  const size_t rowBase = (size_t)blockIdx.y * 128;   // chunk-local out row
  const size_t colBase = (size_t)blockIdx.x * 128;
  f4_t acc[4][4] = {};
  const int lr = lane & 15, lg = lane >> 4;
  for (int k0 = 0; k0 < K; k0 += 32) {
#pragma unroll
    for (int l = 0; l < 2; l++) {
      const int c = tid + l * 256;
      const int r = c >> 2, ko = (c & 3) * 8;
      const int d = k0 + ko;
      const int g = d / DG;
      const int sidx = (((b * NG + g) * NKK) + kk) * NN + r;
      const int y0 = y0buf[sidx];
      const float w = wbuf[sidx];
      float4 a0 = make_float4(0.f, 0.f, 0.f, 0.f), a1 = a0, b0 = a0, b1 = a0;
      if (y0 >= 0) {
        const float* p = &kvrows[((size_t)b * NN + y0) * DIM + d];
        a0 = *(const float4*)p; a1 = *(const float4*)(p + 4);
      }
      if (y0 < NN - 1) {
        const float* p = &kvrows[((size_t)b * NN + y0 + 1) * DIM + d];
        b0 = *(const float4*)p; b1 = *(const float4*)(p + 4);
      }
      const float w0 = 1.0f - w;
      short sv[8];
      sv[0] = f2bf(a0.x * w0 + b0.x * w); sv[1] = f2bf(a0.y * w0 + b0.y * w);
      sv[2] = f2bf(a0.z * w0 + b0.z * w); sv[3] = f2bf(a0.w * w0 + b0.w * w);
      sv[4] = f2bf(a1.x * w0 + b1.x * w); sv[5] = f2bf(a1.y * w0 + b1.y * w);
      sv[6] = f2bf(a1.z * w0 + b1.z * w); sv[7] = f2bf(a1.w * w0 + b1.w * w);
      *(uint4*)&As[r * LDP + ko] = *(const uint4*)&sv[0];
      *(uint4*)&Bs[r * LDP + ko] =
          *(const uint4*)&BT[(colBase + r) * (size_t)K + k0 + ko];
    }
    __syncthreads();
    bf8_t af[4], bfr[4];
#pragma unroll
    for (int mi = 0; mi < 4; mi++)
      af[mi] = *(const bf8_t*)&As[(wm * 64 + mi * 16 + lr) * LDP + lg * 8];
#pragma unroll
    for (int ni = 0; ni < 4; ni++)
      bfr[ni] = *(const bf8_t*)&Bs[(wn * 64 + ni * 16 + lr) * LDP + lg * 8];
#pragma unroll
    for (int mi = 0; mi < 4; mi++)
#pragma unroll
      for (int ni = 0; ni < 4; ni++)
        acc[mi][ni] = __builtin_amdgcn_mfma_f32_16x16x32_bf16(
            af[mi], bfr[ni], acc[mi][ni], 0, 0, 0);
    __syncthreads();
  }
#pragma unroll
  for (int ni = 0; ni < 4; ni++) {
    const size_t col = colBase + wn * 64 + ni * 16 + lr;
    const float bv = bias[col];
#pragma unroll
    for (int mi = 0; mi < 4; mi++) {
#pragma unroll
      for (int r = 0; r < 4; r++) {
        const size_t row = rowBase + wm * 64 + mi * 16 + lg * 4 + r;
        const float v = fmaxf(acc[mi][ni][r] + bv, 0.0f);   // ReLU
        outb[row * Nc + col] = __float2bfloat16(v);
      }
    }
  }
}

// ------- offsets: depthwise conv7 -> gelu -> pointwise -> tanh*4 -> coords --
__global__ __launch_bounds__(256) void offset_kernel(
    const float* __restrict__ qproj, const float* __restrict__ dw_w,
    const float* __restrict__ dw_b, const float* __restrict__ pw_w,
    int* __restrict__ y0buf, float* __restrict__ wbuf)
{
  const int gid = blockIdx.x * 256 + threadIdx.x;  // < B*G*N
  const int n = gid & (NN - 1);
  const int bg = gid >> 7;
  const int b = bg >> 1, g = bg & 1;
  const size_t qb = (size_t)b * NN * DIM + g * DG;
  float acc0 = 0.f, acc1 = 0.f, acc2 = 0.f, acc3 = 0.f;
  for (int c = 0; c < DG; ++c) {
    float wsum = dw_b[c];
#pragma unroll
    for (int tap = 0; tap < KSZ; ++tap) {
      const int np = n - 3 + tap;
      if ((unsigned)np < (unsigned)NN)
        wsum += qproj[qb + (size_t)np * DIM + c] * dw_w[c * KSZ + tap];
    }
    const float gl = geluf(wsum);
    acc0 += pw_w[0 * DG + c] * gl;
    acc1 += pw_w[1 * DG + c] * gl;
    acc2 += pw_w[2 * DG + c] * gl;
    acc3 += pw_w[3 * DG + c] * gl;
  }
  const float accs[4] = {acc0, acc1, acc2, acc3};
#pragma unroll
  for (int kk = 0; kk < NKK; ++kk) {
    const float off = tanhf(accs[kk]) * 4.0f;
    const float vgrid = (float)n + off;
    float vg = 2.0f * vgrid / (float)(NN - 1) - 1.0f;
    vg = fminf(fmaxf(vg, -1.0f), 1.0f);
    const float iy = ((vg + 1.0f) * (float)NN - 1.0f) * 0.5f;
    const float y0f = floorf(iy);
    const int idx = (bg * NKK + kk) * NN + n;
    y0buf[idx] = (int)y0f;
    wbuf[idx] = iy - y0f;
  }
}

// ------- per-position 4-key attention; adds result into qrows (residual) ----
__global__ __launch_bounds__(128) void attn_kernel(
    const float* __restrict__ qproj, const float* __restrict__ k_ch,
    const float* __restrict__ v_ch, const float* __restrict__ attn_scale,
    float* __restrict__ qrows, int bBase)
{
  const int bid = blockIdx.x;
  const int h = bid & 3;
  const int bnl = bid >> 2;                   // local b*N + n
  const int bl = bnl >> 7;
  const int n = bnl & 127;
  const size_t bn = ((size_t)(bBase + bl)) * NN + n;   // global row
  const int t = threadIdx.x;
  const int lane = t & 63, wid = t >> 6;
  __shared__ float red[2][4];
  __shared__ float simsh[4];
  float qv = 0.f;
  if (t < DHH)
    qv = qproj[bn * DIM + h * DHH + t] * 0.10206207261596577f;  // 96^-0.5
#pragma unroll
  for (int kk = 0; kk < NKK; kk++) {
    float pv = 0.f;
    if (t < DHH)
      pv = qv * k_ch[(((size_t)bl * NKK + kk) * NN + n) * DIM + h * DHH + t];
#pragma unroll
    for (int o = 32; o; o >>= 1) pv += __shfl_down(pv, o);
    if (lane == 0) red[wid][kk] = pv;
  }
  __syncthreads();
  if (t == 0) {
#pragma unroll
    for (int kk = 0; kk < NKK; kk++)
      simsh[kk] = (red[0][kk] + red[1][kk]) * 0.08838834764831845f; // 128^-0.5
  }
  __syncthreads();
  const float s0 = simsh[0], s1 = simsh[1], s2 = simsh[2], s3 = simsh[3];
  const float m = fmaxf(fmaxf(s0, s1), fmaxf(s2, s3));
  const float sc = attn_scale[0];
  const float e0 = expf((s0 - m) * sc), e1 = expf((s1 - m) * sc);
  const float e2 = expf((s2 - m) * sc), e3 = expf((s3 - m) * sc);
  const float inv = 1.0f / (e0 + e1 + e2 + e3);
  if (t < DHH) {
    const size_t vb = ((size_t)bl * NKK * NN + n) * DIM + h * DHH + t;
    const size_t stride = (size_t)NN * DIM;
    float o = e0 * inv * v_ch[vb];
    o += e1 * inv * v_ch[vb + stride];
    o += e2 * inv * v_ch[vb + 2 * stride];
    o += e3 * inv * v_ch[vb + 3 * stride];
    const size_t oi = bn * DIM + h * DHH + t;
    qrows[oi] = qrows[oi] + o;      // fused residual: q_pe + attn_out
  }
}

extern "C" void kernel_launch(void* const* d_in, const int* in_sizes, int n_in,
                              void* d_out, int out_size, void* d_ws, size_t ws_size,
                              hipStream_t stream)
{
  const float* q_raw    = (const float*)d_in[0];
  const float* kv_raw   = (const float*)d_in[1];
  const float* emb_q    = (const float*)d_in[2];
  const float* ln_pq_g  = (const float*)d_in[3];
  const float* ln_pq_b  = (const float*)d_in[4];
  const float* emb_kv   = (const float*)d_in[5];
  const float* ln_pkv_g = (const float*)d_in[6];
  const float* ln_pkv_b = (const float*)d_in[7];
  const float* Wq1 = (const float*)d_in[8];   const float* bq1 = (const float*)d_in[9];
  const float* Wq2 = (const float*)d_in[10];  const float* bq2 = (const float*)d_in[11];
  const float* Wk1 = (const float*)d_in[12];  const float* bk1 = (const float*)d_in[13];
  const float* Wk2 = (const float*)d_in[14];  const float* bk2 = (const float*)d_in[15];
  const float* Wv1 = (const float*)d_in[16];  const float* bv1 = (const float*)d_in[17];
  const float* Wv2 = (const float*)d_in[18];  const float* bv2 = (const float*)d_in[19];
  const float* dw_w = (const float*)d_in[20]; const float* dw_b = (const float*)d_in[21];
  const float* pw_w = (const float*)d_in[22];
  const float* ln1_g = (const float*)d_in[23]; const float* ln1_b = (const float*)d_in[24];
  const float* ln2_g = (const float*)d_in[25]; const float* ln2_b = (const float*)d_in[26];
  const float* Wf1 = (const float*)d_in[27];  const float* bf1 = (const float*)d_in[28];
  const float* Wf2 = (const float*)d_in[29];  const float* bf2 = (const float*)d_in[30];
  const float* attn_scale = (const float*)d_in[31];
  float* out = (float*)d_out;

  // ---- dynamic workspace config: pick largest (NCH, NFQ) that fits -------
  const size_t S = (size_t)BB * NN * DIM;            // 12,582,912
  const size_t TAILF = 6 * 73728 + 2 * 393216 + 2 * (size_t)NN * DIM
                     + 2 * (size_t)BB * NG * NKK * NN;
  int NCH = 8, NFQ = 4;
  {
    const int cand[5][2] = {{2, 1}, {4, 1}, {4, 2}, {8, 2}, {8, 4}};
    for (int i = 0; i < 5; i++) {
      const size_t pb = (size_t)125829120 / cand[i][0];
      const size_t pc = S / 2 + (size_t)33554432 / cand[i][1];
      size_t ch = S; if (pb > ch) ch = pb; if (pc > ch) ch = pc;
      const size_t totB = (3 * S + ch + TAILF) * 4;
      if (totB <= ws_size) { NCH = cand[i][0]; NFQ = cand[i][1]; break; }
    }
  }
  const size_t PB = (size_t)125829120 / NCH;
  const size_t PC = S / 2 + (size_t)33554432 / NFQ;
  size_t CHSZ = S; if (PB > CHSZ) CHSZ = PB; if (PC > CHSZ) CHSZ = PC;

  const int MQ = BB * NN;                      // 32768
  const int B_PER_CH = BB / NCH;
  const int BY_PER_CH = B_PER_CH * NKK;
  const int ROWS_PER_CH = BY_PER_CH * NN;      // = 131072/NCH
  const int FROWS = MQ / NFQ;

  // ---- workspace layout (floats), lifetime-aliased ----
  float* wsf = (float*)d_ws;
  float* qrows = wsf;                 // f32 residual rows; later lnout
  float* kvr   = qrows + S;           // f32 kv+pe rows; later res (ln1 out)
  float* qproj = kvr + S;             // f32 q MLP out; later res2
  float* chbase = qproj + S;          // shared chunk region (CHSZ floats)
  // phase a (q MLP):
  __hip_bfloat16* qrows_bf = (__hip_bfloat16*)chbase;
  __hip_bfloat16* scr_bf   = (__hip_bfloat16*)(chbase + S / 2);
  // phase b (k/v chunks):
  __hip_bfloat16* hid_bf = (__hip_bfloat16*)chbase;
  float* k_ch = chbase + (size_t)ROWS_PER_CH * DIM / 2;
  float* v_ch = k_ch + (size_t)ROWS_PER_CH * DIM;
  // phase c (FFN):
  __hip_bfloat16* res_bf = (__hip_bfloat16*)chbase;
  __hip_bfloat16* ffnh   = (__hip_bfloat16*)(chbase + S / 2);
  // tail: bf16 transposed weights, pe, coords
  float* p = chbase + CHSZ;
  __hip_bfloat16* wtq1 = (__hip_bfloat16*)p; p += 73728;
  __hip_bfloat16* wtq2 = (__hip_bfloat16*)p; p += 73728;
  __hip_bfloat16* wtk1 = (__hip_bfloat16*)p; p += 73728;
  __hip_bfloat16* wtk2 = (__hip_bfloat16*)p; p += 73728;
  __hip_bfloat16* wtv1 = (__hip_bfloat16*)p; p += 73728;
  __hip_bfloat16* wtv2 = (__hip_bfloat16*)p; p += 73728;
  __hip_bfloat16* wtf1 = (__hip_bfloat16*)p; p += 393216;
  __hip_bfloat16* wtf2 = (__hip_bfloat16*)p; p += 393216;
  float* peq  = p; p += (size_t)NN * DIM;
  float* pekv = p; p += (size_t)NN * DIM;
  int*   y0buf = (int*)p; p += (size_t)BB * NG * NKK * NN;
  float* wbuf  = p;
  float* res   = kvr;
  float* res2  = qproj;
  float* lnout = qrows;

  // 0) weight convert+transpose to bf16 (graph-safe, every call)
  wtrans_kernel<<<dim3(DIM/32, DIM/32), dim3(32, 8), 0, stream>>>(Wq1, wtq1, DIM, DIM);
  wtrans_kernel<<<dim3(DIM/32, DIM/32), dim3(32, 8), 0, stream>>>(Wq2, wtq2, DIM, DIM);
  wtrans_kernel<<<dim3(DIM/32, DIM/32), dim3(32, 8), 0, stream>>>(Wk1, wtk1, DIM, DIM);
  wtrans_kernel<<<dim3(DIM/32, DIM/32), dim3(32, 8), 0, stream>>>(Wk2, wtk2, DIM, DIM);
  wtrans_kernel<<<dim3(DIM/32, DIM/32), dim3(32, 8), 0, stream>>>(Wv1, wtv1, DIM, DIM);
  wtrans_kernel<<<dim3(DIM/32, DIM/32), dim3(32, 8), 0, stream>>>(Wv2, wtv2, DIM, DIM);
  wtrans_kernel<<<dim3(DFF/32, DIM/32), dim3(32, 8), 0, stream>>>(Wf1, wtf1, DIM, DFF);
  wtrans_kernel<<<dim3(DIM/32, DFF/32), dim3(32, 8), 0, stream>>>(Wf2, wtf2, DFF, DIM);

  // 1) positional-encoding LayerNorms
  ln_rows_kernel<false><<<dim3(NN), dim3(128), 0, stream>>>(
      emb_q, ln_pq_g, ln_pq_b, peq, nullptr);
  ln_rows_kernel<false><<<dim3(NN), dim3(128), 0, stream>>>(
      emb_kv, ln_pkv_g, ln_pkv_b, pekv, nullptr);

  // 2) transpose to rows + add pos-enc (q also emits bf16 for the MLP)
  transpose_addpe<true><<<dim3(NN/32, DIM/32, BB), dim3(32, 8), 0, stream>>>(
      q_raw, peq, qrows, qrows_bf);
  transpose_addpe<false><<<dim3(NN/32, DIM/32, BB), dim3(32, 8), 0, stream>>>(
      kv_raw, pekv, kvr, nullptr);

  // 3) q MLP (bf16 MFMA; hidden bf16, output f32)
  mfma_gemm_kernel<true, false, true><<<dim3(DIM/128, MQ/128), 256, 0, stream>>>(
      qrows_bf, wtq1, bq1, nullptr, nullptr, scr_bf, DIM, DIM);
  mfma_gemm_kernel<false, false, false><<<dim3(DIM/128, MQ/128), 256, 0, stream>>>(
      scr_bf, wtq2, bq2, nullptr, qproj, nullptr, DIM, DIM);

  // 4) offset prediction -> sampling coords (f32)
  offset_kernel<<<dim3(BB * NG * NN / 256), 256, 0, stream>>>(
      qproj, dw_w, dw_b, pw_w, y0buf, wbuf);

  // 5) per batch-chunk: k MLP, v MLP (layer-1 fuses grid-sample), attention
  for (int c = 0; c < NCH; ++c) {
    const int byBase = c * BY_PER_CH;
    mfma_gemm_sampled_kernel<<<dim3(DIM/128, BY_PER_CH), 256, 0, stream>>>(
        kvr, y0buf, wbuf, wtk1, bk1, hid_bf, DIM, DIM, byBase);
    mfma_gemm_kernel<false, false, false><<<dim3(DIM/128, ROWS_PER_CH/128), 256, 0, stream>>>(
        hid_bf, wtk2, bk2, nullptr, k_ch, nullptr, DIM, DIM);
    mfma_gemm_sampled_kernel<<<dim3(DIM/128, BY_PER_CH), 256, 0, stream>>>(
        kvr, y0buf, wbuf, wtv1, bv1, hid_bf, DIM, DIM, byBase);
    mfma_gemm_kernel<false, false, false><<<dim3(DIM/128, ROWS_PER_CH/128), 256, 0, stream>>>(
        hid_bf, wtv2, bv2, nullptr, v_ch, nullptr, DIM, DIM);
    attn_kernel<<<dim3(B_PER_CH * NN * NH), 128, 0, stream>>>(
        qproj, k_ch, v_ch, attn_scale, qrows, c * B_PER_CH);
  }

  // 6) res = LN(q_pe + attn_out); also emit bf16 for FFN input
  ln_rows_kernel<true><<<dim3(MQ), dim3(128), 0, stream>>>(
      qrows, ln1_g, ln1_b, res, res_bf);

  // 7) FFN in row-chunks (bf16 MFMA), residual fused into second GEMM
  for (int q = 0; q < NFQ; ++q) {
    const size_t roff = (size_t)q * FROWS;
    mfma_gemm_kernel<true, false, true><<<dim3(DFF/128, FROWS/128), 256, 0, stream>>>(
        res_bf + roff * DIM, wtf1, bf1, nullptr, nullptr, ffnh, DIM, DFF);
    mfma_gemm_kernel<false, true, false><<<dim3(DIM/128, FROWS/128), 256, 0, stream>>>(
        ffnh, wtf2, bf2, res + roff * DIM, res2 + roff * DIM, nullptr, DFF, DIM);
  }

  // 8) final LN + transpose back to (B, DIM, N)
  ln_rows_kernel<false><<<dim3(MQ), dim3(128), 0, stream>>>(
      res2, ln2_g, ln2_b, lnout, nullptr);
  transpose_to_cf<<<dim3(NN/32, DIM/32, BB), dim3(32, 8), 0, stream>>>(
      lnout, out);
}

// Round 9
// 1451.168 us; speedup vs baseline: 3.8712x; 1.0966x over previous
//
#include <hip/hip_runtime.h>
#include <hip/hip_bf16.h>
#include <cstdint>
#include <cstddef>

#define BB   256
#define DIM  384
#define NN   128
#define NH   4
#define NG   2
#define NKK  4
#define DHH  96
#define DG   192
#define KSZ  7
#define DFF  2048

typedef __attribute__((ext_vector_type(8))) short bf8_t;   // 8 bf16 (4 VGPR)
typedef __attribute__((ext_vector_type(4))) float f4_t;    // 4 f32 acc

static __device__ __forceinline__ float geluf(float x) {
  return 0.5f * x * (1.0f + erff(x * 0.70710678118654752440f));
}
static __device__ __forceinline__ short f2bf(float f) {
  union { __hip_bfloat16 h; short s; } u;
  u.h = __float2bfloat16(f);
  return u.s;
}

// ---------------- LayerNorm rows of 384; optional secondary bf16 output -----
template<bool WB>
__global__ __launch_bounds__(128) void ln_rows_kernel(
    const float* __restrict__ X,
    const float* __restrict__ gam, const float* __restrict__ bet,
    float* __restrict__ out, __hip_bfloat16* __restrict__ out2)
{
  const int row = blockIdx.x;
  const int t = threadIdx.x;
  const size_t base = (size_t)row * DIM;
  float x0 = X[base + t], x1 = X[base + t + 128], x2 = X[base + t + 256];
  __shared__ float ws[2];
  float s = x0 + x1 + x2;
#pragma unroll
  for (int o = 32; o; o >>= 1) s += __shfl_down(s, o);
  if ((t & 63) == 0) ws[t >> 6] = s;
  __syncthreads();
  const float m = (ws[0] + ws[1]) * (1.0f / DIM);
  __syncthreads();
  const float d0 = x0 - m, d1 = x1 - m, d2 = x2 - m;
  float v = d0 * d0 + d1 * d1 + d2 * d2;
#pragma unroll
  for (int o = 32; o; o >>= 1) v += __shfl_down(v, o);
  if ((t & 63) == 0) ws[t >> 6] = v;
  __syncthreads();
  const float var = (ws[0] + ws[1]) * (1.0f / DIM);
  const float rs = rsqrtf(var + 1e-5f);
  const float o0 = d0 * rs * gam[t]       + bet[t];
  const float o1 = d1 * rs * gam[t + 128] + bet[t + 128];
  const float o2 = d2 * rs * gam[t + 256] + bet[t + 256];
  out[base + t] = o0; out[base + t + 128] = o1; out[base + t + 256] = o2;
  if (WB) {
    out2[base + t]       = __float2bfloat16(o0);
    out2[base + t + 128] = __float2bfloat16(o1);
    out2[base + t + 256] = __float2bfloat16(o2);
  }
}

// ---------------- (B,DIM,N) + pe(N,DIM) -> rows (B,N,DIM) (+bf16 copy) ------
template<bool WB>
__global__ __launch_bounds__(256) void transpose_addpe(
    const float* __restrict__ X, const float* __restrict__ pe,
    float* __restrict__ out, __hip_bfloat16* __restrict__ outb)
{
  __shared__ float tile[32][33];
  const int b = blockIdx.z;
  const int n0 = blockIdx.x * 32, d0 = blockIdx.y * 32;
  const int tx = threadIdx.x, ty = threadIdx.y;   // 32 x 8
#pragma unroll
  for (int i = 0; i < 4; i++) {
    const int d = d0 + ty + i * 8;
    tile[ty + i * 8][tx] = X[(size_t)b * DIM * NN + (size_t)d * NN + n0 + tx];
  }
  __syncthreads();
#pragma unroll
  for (int i = 0; i < 4; i++) {
    const int n = n0 + ty + i * 8;
    const int d = d0 + tx;
    const float v = tile[tx][ty + i * 8] + pe[n * DIM + d];
    out[((size_t)b * NN + n) * DIM + d] = v;
    if (WB) outb[((size_t)b * NN + n) * DIM + d] = __float2bfloat16(v);
  }
}

// ---------------- rows (B,N,DIM) -> (B,DIM,N) -------------------------------
__global__ __launch_bounds__(256) void transpose_to_cf(
    const float* __restrict__ rows, float* __restrict__ out)
{
  __shared__ float tile[32][33];
  const int b = blockIdx.z;
  const int n0 = blockIdx.x * 32, d0 = blockIdx.y * 32;
  const int tx = threadIdx.x, ty = threadIdx.y;
#pragma unroll
  for (int i = 0; i < 4; i++) {
    const int n = n0 + ty + i * 8;
    tile[ty + i * 8][tx] = rows[((size_t)b * NN + n) * DIM + d0 + tx];
  }
  __syncthreads();
#pragma unroll
  for (int i = 0; i < 4; i++) {
    const int d = d0 + ty + i * 8;
    out[(size_t)b * DIM * NN + (size_t)d * NN + n0 + tx] = tile[tx][ty + i * 8];
  }
}

// ---------------- W (K,N) f32 -> WT (N,K) bf16 ------------------------------
__global__ __launch_bounds__(256) void wtrans_kernel(
    const float* __restrict__ W, __hip_bfloat16* __restrict__ WT, int K, int N)
{
  __shared__ float tile[32][33];
  const int n0 = blockIdx.x * 32, k0 = blockIdx.y * 32;
  const int tx = threadIdx.x, ty = threadIdx.y;   // 32 x 8
#pragma unroll
  for (int i = 0; i < 4; i++)
    tile[ty + i * 8][tx] = W[(size_t)(k0 + ty + i * 8) * N + n0 + tx];
  __syncthreads();
#pragma unroll
  for (int i = 0; i < 4; i++)
    WT[(size_t)(n0 + ty + i * 8) * K + k0 + tx] =
        __float2bfloat16(tile[tx][ty + i * 8]);
}

// ---------------- MFMA GEMM: C = act(A @ BT^T + bias) (+resid) --------------
// A [M][K] bf16 rm, BT [N][K] bf16 rm, bias f32. 256 thr = 4 waves (2x2),
// 128x128 tile, BK=32, 16x16x32 MFMA. K%32==0, M%128==0, N%128==0.
#define LDP 40   // LDS row pitch in bf16 (pad 32 -> 40, conflict-free)
template<bool RELU, bool RES, bool OUTBF>
__global__ __launch_bounds__(256) void mfma_gemm_kernel(
    const __hip_bfloat16* __restrict__ A, const __hip_bfloat16* __restrict__ BT,
    const float* __restrict__ bias, const float* __restrict__ resid,
    float* __restrict__ outf, __hip_bfloat16* __restrict__ outb,
    int K, int Nc)
{
  __shared__ __align__(16) short As[128 * LDP];
  __shared__ __align__(16) short Bs[128 * LDP];
  const int tid = threadIdx.x;
  const int lane = tid & 63, wid = tid >> 6;
  const int wm = wid >> 1, wn = wid & 1;
  const size_t rowBase = (size_t)blockIdx.y * 128;
  const size_t colBase = (size_t)blockIdx.x * 128;
  f4_t acc[4][4] = {};
  const int lr = lane & 15, lg = lane >> 4;     // frag row/col, k-group
  for (int k0 = 0; k0 < K; k0 += 32) {
#pragma unroll
    for (int l = 0; l < 2; l++) {
      const int c = tid + l * 256;
      const int r = c >> 2, ko = (c & 3) * 8;
      *(uint4*)&As[r * LDP + ko] =
          *(const uint4*)&A[(rowBase + r) * (size_t)K + k0 + ko];
      *(uint4*)&Bs[r * LDP + ko] =
          *(const uint4*)&BT[(colBase + r) * (size_t)K + k0 + ko];
    }
    __syncthreads();
    bf8_t af[4], bfr[4];
#pragma unroll
    for (int mi = 0; mi < 4; mi++)
      af[mi] = *(const bf8_t*)&As[(wm * 64 + mi * 16 + lr) * LDP + lg * 8];
#pragma unroll
    for (int ni = 0; ni < 4; ni++)
      bfr[ni] = *(const bf8_t*)&Bs[(wn * 64 + ni * 16 + lr) * LDP + lg * 8];
#pragma unroll
    for (int mi = 0; mi < 4; mi++)
#pragma unroll
      for (int ni = 0; ni < 4; ni++)
        acc[mi][ni] = __builtin_amdgcn_mfma_f32_16x16x32_bf16(
            af[mi], bfr[ni], acc[mi][ni], 0, 0, 0);
    __syncthreads();
  }
#pragma unroll
  for (int ni = 0; ni < 4; ni++) {
    const size_t col = colBase + wn * 64 + ni * 16 + lr;
    const float bv = bias[col];
#pragma unroll
    for (int mi = 0; mi < 4; mi++) {
#pragma unroll
      for (int r = 0; r < 4; r++) {
        const size_t row = rowBase + wm * 64 + mi * 16 + lg * 4 + r;
        float v = acc[mi][ni][r] + bv;
        if (RELU) v = fmaxf(v, 0.0f);
        if (RES) v += resid[row * Nc + col];
        if (OUTBF) outb[row * Nc + col] = __float2bfloat16(v);
        else       outf[row * Nc + col] = v;
      }
    }
  }
}

// ------- MFMA GEMM w/ bilinear-sampled A (fused grid_sample), k/v layer-1 ---
// by-unit = byBase+blockIdx.y encodes (b,kk); tile rows are n=0..127.
__global__ __launch_bounds__(256) void mfma_gemm_sampled_kernel(
    const float* __restrict__ kvrows, const int* __restrict__ y0buf,
    const float* __restrict__ wbuf, const __hip_bfloat16* __restrict__ BT,
    const float* __restrict__ bias, __hip_bfloat16* __restrict__ outb,
    int K, int Nc, int byBase)
{
  __shared__ __align__(16) short As[128 * LDP];
  __shared__ __align__(16) short Bs[128 * LDP];
  const int tid = threadIdx.x;
  const int lane = tid & 63, wid = tid >> 6;
  const int wm = wid >> 1, wn = wid & 1;
  const int byG = blockIdx.y + byBase;
  const int b = byG >> 2, kk = byG & 3;
  const size_t rowBase = (size_t)blockIdx.y * 128;   // chunk-local out row
  const size_t colBase = (size_t)blockIdx.x * 128;
  f4_t acc[4][4] = {};
  const int lr = lane & 15, lg = lane >> 4;
  for (int k0 = 0; k0 < K; k0 += 32) {
#pragma unroll
    for (int l = 0; l < 2; l++) {
      const int c = tid + l * 256;
      const int r = c >> 2, ko = (c & 3) * 8;
      const int d = k0 + ko;
      const int g = d / DG;
      const int sidx = (((b * NG + g) * NKK) + kk) * NN + r;
      const int y0 = y0buf[sidx];
      const float w = wbuf[sidx];
      float4 a0 = make_float4(0.f, 0.f, 0.f, 0.f), a1 = a0, b0 = a0, b1 = a0;
      if (y0 >= 0) {
        const float* p = &kvrows[((size_t)b * NN + y0) * DIM + d];
        a0 = *(const float4*)p; a1 = *(const float4*)(p + 4);
      }
      if (y0 < NN - 1) {
        const float* p = &kvrows[((size_t)b * NN + y0 + 1) * DIM + d];
        b0 = *(const float4*)p; b1 = *(const float4*)(p + 4);
      }
      const float w0 = 1.0f - w;
      short sv[8];
      sv[0] = f2bf(a0.x * w0 + b0.x * w); sv[1] = f2bf(a0.y * w0 + b0.y * w);
      sv[2] = f2bf(a0.z * w0 + b0.z * w); sv[3] = f2bf(a0.w * w0 + b0.w * w);
      sv[4] = f2bf(a1.x * w0 + b1.x * w); sv[5] = f2bf(a1.y * w0 + b1.y * w);
      sv[6] = f2bf(a1.z * w0 + b1.z * w); sv[7] = f2bf(a1.w * w0 + b1.w * w);
      *(uint4*)&As[r * LDP + ko] = *(const uint4*)&sv[0];
      *(uint4*)&Bs[r * LDP + ko] =
          *(const uint4*)&BT[(colBase + r) * (size_t)K + k0 + ko];
    }
    __syncthreads();
    bf8_t af[4], bfr[4];
#pragma unroll
    for (int mi = 0; mi < 4; mi++)
      af[mi] = *(const bf8_t*)&As[(wm * 64 + mi * 16 + lr) * LDP + lg * 8];
#pragma unroll
    for (int ni = 0; ni < 4; ni++)
      bfr[ni] = *(const bf8_t*)&Bs[(wn * 64 + ni * 16 + lr) * LDP + lg * 8];
#pragma unroll
    for (int mi = 0; mi < 4; mi++)
#pragma unroll
      for (int ni = 0; ni < 4; ni++)
        acc[mi][ni] = __builtin_amdgcn_mfma_f32_16x16x32_bf16(
            af[mi], bfr[ni], acc[mi][ni], 0, 0, 0);
    __syncthreads();
  }
#pragma unroll
  for (int ni = 0; ni < 4; ni++) {
    const size_t col = colBase + wn * 64 + ni * 16 + lr;
    const float bv = bias[col];
#pragma unroll
    for (int mi = 0; mi < 4; mi++) {
#pragma unroll
      for (int r = 0; r < 4; r++) {
        const size_t row = rowBase + wm * 64 + mi * 16 + lg * 4 + r;
        const float v = fmaxf(acc[mi][ni][r] + bv, 0.0f);   // ReLU
        outb[row * Nc + col] = __float2bfloat16(v);
      }
    }
  }
}

// ------- offsets v2: channel-per-lane, sliding window, wave reduce ----------
// Block = one (b,g): 192 threads (3 waves), lane owns channel c.
// Coalesced loads (lanes read contiguous 768B per n-step), each element read
// exactly once; per-wave partial sums -> 6KB LDS -> final 128-thread pass.
__global__ __launch_bounds__(192) void offset2_kernel(
    const float* __restrict__ qproj, const float* __restrict__ dw_w,
    const float* __restrict__ dw_b, const float* __restrict__ pw_w,
    int* __restrict__ y0buf, float* __restrict__ wbuf)
{
  const int bg = blockIdx.x;               // b*NG + g
  const int b = bg >> 1, g = bg & 1;
  const int t = threadIdx.x;               // 0..191  (= channel c)
  const int lane = t & 63, wv = t >> 6;
  __shared__ float part[NN][3][4];         // per-n, per-wave, per-k partials

  const float* qp = qproj + (size_t)b * NN * DIM + g * DG + t;  // stride DIM
  float dwc[KSZ];
#pragma unroll
  for (int tap = 0; tap < KSZ; ++tap) dwc[tap] = dw_w[t * KSZ + tap];
  const float db = dw_b[t];
  const float pw0 = pw_w[0 * DG + t], pw1 = pw_w[1 * DG + t];
  const float pw2 = pw_w[2 * DG + t], pw3 = pw_w[3 * DG + t];

  float win[KSZ];
  win[0] = 0.f; win[1] = 0.f; win[2] = 0.f;
  win[3] = qp[0 * DIM]; win[4] = qp[1 * DIM]; win[5] = qp[2 * DIM];
  win[6] = 0.f;
  for (int n = 0; n < NN; ++n) {
    win[6] = (n + 3 < NN) ? qp[(size_t)(n + 3) * DIM] : 0.f;
    float y = db;
#pragma unroll
    for (int i = 0; i < KSZ; ++i) y = fmaf(win[i], dwc[i], y);
    const float gl = geluf(y);
    float p0 = pw0 * gl, p1 = pw1 * gl, p2 = pw2 * gl, p3 = pw3 * gl;
#pragma unroll
    for (int o = 32; o; o >>= 1) {
      p0 += __shfl_down(p0, o);
      p1 += __shfl_down(p1, o);
      p2 += __shfl_down(p2, o);
      p3 += __shfl_down(p3, o);
    }
    if (lane == 0) {
      part[n][wv][0] = p0; part[n][wv][1] = p1;
      part[n][wv][2] = p2; part[n][wv][3] = p3;
    }
#pragma unroll
    for (int i = 0; i < KSZ - 1; ++i) win[i] = win[i + 1];
  }
  __syncthreads();
  if (t < NN) {
    const int n = t;
#pragma unroll
    for (int kk = 0; kk < NKK; ++kk) {
      const float acc = part[n][0][kk] + part[n][1][kk] + part[n][2][kk];
      const float off = tanhf(acc) * 4.0f;
      const float vgrid = (float)n + off;
      float vg = 2.0f * vgrid / (float)(NN - 1) - 1.0f;
      vg = fminf(fmaxf(vg, -1.0f), 1.0f);
      const float iy = ((vg + 1.0f) * (float)NN - 1.0f) * 0.5f;
      const float y0f = floorf(iy);
      const int idx = (bg * NKK + kk) * NN + n;
      y0buf[idx] = (int)y0f;
      wbuf[idx] = iy - y0f;
    }
  }
}

// ------- per-position 4-key attention; adds result into qrows (residual) ----
__global__ __launch_bounds__(128) void attn_kernel(
    const float* __restrict__ qproj, const float* __restrict__ k_ch,
    const float* __restrict__ v_ch, const float* __restrict__ attn_scale,
    float* __restrict__ qrows, int bBase)
{
  const int bid = blockIdx.x;
  const int h = bid & 3;
  const int bnl = bid >> 2;                   // local b*N + n
  const int bl = bnl >> 7;
  const int n = bnl & 127;
  const size_t bn = ((size_t)(bBase + bl)) * NN + n;   // global row
  const int t = threadIdx.x;
  const int lane = t & 63, wid = t >> 6;
  __shared__ float red[2][4];
  __shared__ float simsh[4];
  float qv = 0.f;
  if (t < DHH)
    qv = qproj[bn * DIM + h * DHH + t] * 0.10206207261596577f;  // 96^-0.5
#pragma unroll
  for (int kk = 0; kk < NKK; kk++) {
    float pv = 0.f;
    if (t < DHH)
      pv = qv * k_ch[(((size_t)bl * NKK + kk) * NN + n) * DIM + h * DHH + t];
#pragma unroll
    for (int o = 32; o; o >>= 1) pv += __shfl_down(pv, o);
    if (lane == 0) red[wid][kk] = pv;
  }
  __syncthreads();
  if (t == 0) {
#pragma unroll
    for (int kk = 0; kk < NKK; kk++)
      simsh[kk] = (red[0][kk] + red[1][kk]) * 0.08838834764831845f; // 128^-0.5
  }
  __syncthreads();
  const float s0 = simsh[0], s1 = simsh[1], s2 = simsh[2], s3 = simsh[3];
  const float m = fmaxf(fmaxf(s0, s1), fmaxf(s2, s3));
  const float sc = attn_scale[0];
  const float e0 = expf((s0 - m) * sc), e1 = expf((s1 - m) * sc);
  const float e2 = expf((s2 - m) * sc), e3 = expf((s3 - m) * sc);
  const float inv = 1.0f / (e0 + e1 + e2 + e3);
  if (t < DHH) {
    const size_t vb = ((size_t)bl * NKK * NN + n) * DIM + h * DHH + t;
    const size_t stride = (size_t)NN * DIM;
    float o = e0 * inv * v_ch[vb];
    o += e1 * inv * v_ch[vb + stride];
    o += e2 * inv * v_ch[vb + 2 * stride];
    o += e3 * inv * v_ch[vb + 3 * stride];
    const size_t oi = bn * DIM + h * DHH + t;
    qrows[oi] = qrows[oi] + o;      // fused residual: q_pe + attn_out
  }
}

extern "C" void kernel_launch(void* const* d_in, const int* in_sizes, int n_in,
                              void* d_out, int out_size, void* d_ws, size_t ws_size,
                              hipStream_t stream)
{
  const float* q_raw    = (const float*)d_in[0];
  const float* kv_raw   = (const float*)d_in[1];
  const float* emb_q    = (const float*)d_in[2];
  const float* ln_pq_g  = (const float*)d_in[3];
  const float* ln_pq_b  = (const float*)d_in[4];
  const float* emb_kv   = (const float*)d_in[5];
  const float* ln_pkv_g = (const float*)d_in[6];
  const float* ln_pkv_b = (const float*)d_in[7];
  const float* Wq1 = (const float*)d_in[8];   const float* bq1 = (const float*)d_in[9];
  const float* Wq2 = (const float*)d_in[10];  const float* bq2 = (const float*)d_in[11];
  const float* Wk1 = (const float*)d_in[12];  const float* bk1 = (const float*)d_in[13];
  const float* Wk2 = (const float*)d_in[14];  const float* bk2 = (const float*)d_in[15];
  const float* Wv1 = (const float*)d_in[16];  const float* bv1 = (const float*)d_in[17];
  const float* Wv2 = (const float*)d_in[18];  const float* bv2 = (const float*)d_in[19];
  const float* dw_w = (const float*)d_in[20]; const float* dw_b = (const float*)d_in[21];
  const float* pw_w = (const float*)d_in[22];
  const float* ln1_g = (const float*)d_in[23]; const float* ln1_b = (const float*)d_in[24];
  const float* ln2_g = (const float*)d_in[25]; const float* ln2_b = (const float*)d_in[26];
  const float* Wf1 = (const float*)d_in[27];  const float* bf1 = (const float*)d_in[28];
  const float* Wf2 = (const float*)d_in[29];  const float* bf2 = (const float*)d_in[30];
  const float* attn_scale = (const float*)d_in[31];
  float* out = (float*)d_out;

  // ---- dynamic workspace config: pick largest (NCH, NFQ) that fits -------
  const size_t S = (size_t)BB * NN * DIM;            // 12,582,912
  const size_t TAILF = 6 * 73728 + 2 * 393216 + 2 * (size_t)NN * DIM
                     + 2 * (size_t)BB * NG * NKK * NN;
  int NCH = 8, NFQ = 4;
  {
    const int cand[5][2] = {{2, 1}, {4, 1}, {4, 2}, {8, 2}, {8, 4}};
    for (int i = 0; i < 5; i++) {
      const size_t pb = (size_t)125829120 / cand[i][0];
      const size_t pc = S / 2 + (size_t)33554432 / cand[i][1];
      size_t ch = S; if (pb > ch) ch = pb; if (pc > ch) ch = pc;
      const size_t totB = (3 * S + ch + TAILF) * 4;
      if (totB <= ws_size) { NCH = cand[i][0]; NFQ = cand[i][1]; break; }
    }
  }
  const size_t PB = (size_t)125829120 / NCH;
  const size_t PC = S / 2 + (size_t)33554432 / NFQ;
  size_t CHSZ = S; if (PB > CHSZ) CHSZ = PB; if (PC > CHSZ) CHSZ = PC;

  const int MQ = BB * NN;                      // 32768
  const int B_PER_CH = BB / NCH;
  const int BY_PER_CH = B_PER_CH * NKK;
  const int ROWS_PER_CH = BY_PER_CH * NN;      // = 131072/NCH
  const int FROWS = MQ / NFQ;

  // ---- workspace layout (floats), lifetime-aliased ----
  float* wsf = (float*)d_ws;
  float* qrows = wsf;                 // f32 residual rows; later lnout
  float* kvr   = qrows + S;           // f32 kv+pe rows; later res (ln1 out)
  float* qproj = kvr + S;             // f32 q MLP out; later res2
  float* chbase = qproj + S;          // shared chunk region (CHSZ floats)
  // phase a (q MLP):
  __hip_bfloat16* qrows_bf = (__hip_bfloat16*)chbase;
  __hip_bfloat16* scr_bf   = (__hip_bfloat16*)(chbase + S / 2);
  // phase b (k/v chunks):
  __hip_bfloat16* hid_bf = (__hip_bfloat16*)chbase;
  float* k_ch = chbase + (size_t)ROWS_PER_CH * DIM / 2;
  float* v_ch = k_ch + (size_t)ROWS_PER_CH * DIM;
  // phase c (FFN):
  __hip_bfloat16* res_bf = (__hip_bfloat16*)chbase;
  __hip_bfloat16* ffnh   = (__hip_bfloat16*)(chbase + S / 2);
  // tail: bf16 transposed weights, pe, coords
  float* p = chbase + CHSZ;
  __hip_bfloat16* wtq1 = (__hip_bfloat16*)p; p += 73728;
  __hip_bfloat16* wtq2 = (__hip_bfloat16*)p; p += 73728;
  __hip_bfloat16* wtk1 = (__hip_bfloat16*)p; p += 73728;
  __hip_bfloat16* wtk2 = (__hip_bfloat16*)p; p += 73728;
  __hip_bfloat16* wtv1 = (__hip_bfloat16*)p; p += 73728;
  __hip_bfloat16* wtv2 = (__hip_bfloat16*)p; p += 73728;
  __hip_bfloat16* wtf1 = (__hip_bfloat16*)p; p += 393216;
  __hip_bfloat16* wtf2 = (__hip_bfloat16*)p; p += 393216;
  float* peq  = p; p += (size_t)NN * DIM;
  float* pekv = p; p += (size_t)NN * DIM;
  int*   y0buf = (int*)p; p += (size_t)BB * NG * NKK * NN;
  float* wbuf  = p;
  float* res   = kvr;
  float* res2  = qproj;
  float* lnout = qrows;

  // 0) weight convert+transpose to bf16 (graph-safe, every call)
  wtrans_kernel<<<dim3(DIM/32, DIM/32), dim3(32, 8), 0, stream>>>(Wq1, wtq1, DIM, DIM);
  wtrans_kernel<<<dim3(DIM/32, DIM/32), dim3(32, 8), 0, stream>>>(Wq2, wtq2, DIM, DIM);
  wtrans_kernel<<<dim3(DIM/32, DIM/32), dim3(32, 8), 0, stream>>>(Wk1, wtk1, DIM, DIM);
  wtrans_kernel<<<dim3(DIM/32, DIM/32), dim3(32, 8), 0, stream>>>(Wk2, wtk2, DIM, DIM);
  wtrans_kernel<<<dim3(DIM/32, DIM/32), dim3(32, 8), 0, stream>>>(Wv1, wtv1, DIM, DIM);
  wtrans_kernel<<<dim3(DIM/32, DIM/32), dim3(32, 8), 0, stream>>>(Wv2, wtv2, DIM, DIM);
  wtrans_kernel<<<dim3(DFF/32, DIM/32), dim3(32, 8), 0, stream>>>(Wf1, wtf1, DIM, DFF);
  wtrans_kernel<<<dim3(DIM/32, DFF/32), dim3(32, 8), 0, stream>>>(Wf2, wtf2, DFF, DIM);

  // 1) positional-encoding LayerNorms
  ln_rows_kernel<false><<<dim3(NN), dim3(128), 0, stream>>>(
      emb_q, ln_pq_g, ln_pq_b, peq, nullptr);
  ln_rows_kernel<false><<<dim3(NN), dim3(128), 0, stream>>>(
      emb_kv, ln_pkv_g, ln_pkv_b, pekv, nullptr);

  // 2) transpose to rows + add pos-enc (q also emits bf16 for the MLP)
  transpose_addpe<true><<<dim3(NN/32, DIM/32, BB), dim3(32, 8), 0, stream>>>(
      q_raw, peq, qrows, qrows_bf);
  transpose_addpe<false><<<dim3(NN/32, DIM/32, BB), dim3(32, 8), 0, stream>>>(
      kv_raw, pekv, kvr, nullptr);

  // 3) q MLP (bf16 MFMA; hidden bf16, output f32)
  mfma_gemm_kernel<true, false, true><<<dim3(DIM/128, MQ/128), 256, 0, stream>>>(
      qrows_bf, wtq1, bq1, nullptr, nullptr, scr_bf, DIM, DIM);
  mfma_gemm_kernel<false, false, false><<<dim3(DIM/128, MQ/128), 256, 0, stream>>>(
      scr_bf, wtq2, bq2, nullptr, qproj, nullptr, DIM, DIM);

  // 4) offset prediction -> sampling coords (f32, channel-per-lane)
  offset2_kernel<<<dim3(BB * NG), dim3(192), 0, stream>>>(
      qproj, dw_w, dw_b, pw_w, y0buf, wbuf);

  // 5) per batch-chunk: k MLP, v MLP (layer-1 fuses grid-sample), attention
  for (int c = 0; c < NCH; ++c) {
    const int byBase = c * BY_PER_CH;
    mfma_gemm_sampled_kernel<<<dim3(DIM/128, BY_PER_CH), 256, 0, stream>>>(
        kvr, y0buf, wbuf, wtk1, bk1, hid_bf, DIM, DIM, byBase);
    mfma_gemm_kernel<false, false, false><<<dim3(DIM/128, ROWS_PER_CH/128), 256, 0, stream>>>(
        hid_bf, wtk2, bk2, nullptr, k_ch, nullptr, DIM, DIM);
    mfma_gemm_sampled_kernel<<<dim3(DIM/128, BY_PER_CH), 256, 0, stream>>>(
        kvr, y0buf, wbuf, wtv1, bv1, hid_bf, DIM, DIM, byBase);
    mfma_gemm_kernel<false, false, false><<<dim3(DIM/128, ROWS_PER_CH/128), 256, 0, stream>>>(
        hid_bf, wtv2, bv2, nullptr, v_ch, nullptr, DIM, DIM);
    attn_kernel<<<dim3(B_PER_CH * NN * NH), 128, 0, stream>>>(
        qproj, k_ch, v_ch, attn_scale, qrows, c * B_PER_CH);
  }

  // 6) res = LN(q_pe + attn_out); also emit bf16 for FFN input
  ln_rows_kernel<true><<<dim3(MQ), dim3(128), 0, stream>>>(
      qrows, ln1_g, ln1_b, res, res_bf);

  // 7) FFN in row-chunks (bf16 MFMA), residual fused into second GEMM
  for (int q = 0; q < NFQ; ++q) {
    const size_t roff = (size_t)q * FROWS;
    mfma_gemm_kernel<true, false, true><<<dim3(DFF/128, FROWS/128), 256, 0, stream>>>(
        res_bf + roff * DIM, wtf1, bf1, nullptr, nullptr, ffnh, DIM, DFF);
    mfma_gemm_kernel<false, true, false><<<dim3(DIM/128, FROWS/128), 256, 0, stream>>>(
        ffnh, wtf2, bf2, res + roff * DIM, res2 + roff * DIM, nullptr, DFF, DIM);
  }

  // 8) final LN + transpose back to (B, DIM, N)
  ln_rows_kernel<false><<<dim3(MQ), dim3(128), 0, stream>>>(
      res2, ln2_g, ln2_b, lnout, nullptr);
  transpose_to_cf<<<dim3(NN/32, DIM/32, BB), dim3(32, 8), 0, stream>>>(
      lnout, out);
}

// Round 10
// 1265.623 us; speedup vs baseline: 4.4387x; 1.1466x over previous
//
#include <hip/hip_runtime.h>
#include <hip/hip_bf16.h>
#include <cstdint>
#include <cstddef>

#define BB   256
#define DIM  384
#define NN   128
#define NH   4
#define NG   2
#define NKK  4
#define DHH  96
#define DG   192
#define KSZ  7
#define DFF  2048

typedef __attribute__((ext_vector_type(8))) short bf8_t;   // 8 bf16 (4 VGPR)
typedef __attribute__((ext_vector_type(4))) float f4_t;    // 4 f32 acc

static __device__ __forceinline__ float geluf(float x) {
  return 0.5f * x * (1.0f + erff(x * 0.70710678118654752440f));
}
static __device__ __forceinline__ short f2bf(float f) {
  union { __hip_bfloat16 h; short s; } u;
  u.h = __float2bfloat16(f);
  return u.s;
}

// ---------------- LayerNorm rows of 384; optional secondary bf16 output -----
template<bool WB>
__global__ __launch_bounds__(128) void ln_rows_kernel(
    const float* __restrict__ X,
    const float* __restrict__ gam, const float* __restrict__ bet,
    float* __restrict__ out, __hip_bfloat16* __restrict__ out2)
{
  const int row = blockIdx.x;
  const int t = threadIdx.x;
  const size_t base = (size_t)row * DIM;
  float x0 = X[base + t], x1 = X[base + t + 128], x2 = X[base + t + 256];
  __shared__ float ws[2];
  float s = x0 + x1 + x2;
#pragma unroll
  for (int o = 32; o; o >>= 1) s += __shfl_down(s, o);
  if ((t & 63) == 0) ws[t >> 6] = s;
  __syncthreads();
  const float m = (ws[0] + ws[1]) * (1.0f / DIM);
  __syncthreads();
  const float d0 = x0 - m, d1 = x1 - m, d2 = x2 - m;
  float v = d0 * d0 + d1 * d1 + d2 * d2;
#pragma unroll
  for (int o = 32; o; o >>= 1) v += __shfl_down(v, o);
  if ((t & 63) == 0) ws[t >> 6] = v;
  __syncthreads();
  const float var = (ws[0] + ws[1]) * (1.0f / DIM);
  const float rs = rsqrtf(var + 1e-5f);
  const float o0 = d0 * rs * gam[t]       + bet[t];
  const float o1 = d1 * rs * gam[t + 128] + bet[t + 128];
  const float o2 = d2 * rs * gam[t + 256] + bet[t + 256];
  out[base + t] = o0; out[base + t + 128] = o1; out[base + t + 256] = o2;
  if (WB) {
    out2[base + t]       = __float2bfloat16(o0);
    out2[base + t + 128] = __float2bfloat16(o1);
    out2[base + t + 256] = __float2bfloat16(o2);
  }
}

// ---------------- (B,DIM,N) + pe(N,DIM) -> rows (B,N,DIM) (+bf16 copy) ------
template<bool WB>
__global__ __launch_bounds__(256) void transpose_addpe(
    const float* __restrict__ X, const float* __restrict__ pe,
    float* __restrict__ out, __hip_bfloat16* __restrict__ outb)
{
  __shared__ float tile[32][33];
  const int b = blockIdx.z;
  const int n0 = blockIdx.x * 32, d0 = blockIdx.y * 32;
  const int tx = threadIdx.x, ty = threadIdx.y;   // 32 x 8
#pragma unroll
  for (int i = 0; i < 4; i++) {
    const int d = d0 + ty + i * 8;
    tile[ty + i * 8][tx] = X[(size_t)b * DIM * NN + (size_t)d * NN + n0 + tx];
  }
  __syncthreads();
#pragma unroll
  for (int i = 0; i < 4; i++) {
    const int n = n0 + ty + i * 8;
    const int d = d0 + tx;
    const float v = tile[tx][ty + i * 8] + pe[n * DIM + d];
    out[((size_t)b * NN + n) * DIM + d] = v;
    if (WB) outb[((size_t)b * NN + n) * DIM + d] = __float2bfloat16(v);
  }
}

// ---------------- rows (B,N,DIM) -> (B,DIM,N) -------------------------------
__global__ __launch_bounds__(256) void transpose_to_cf(
    const float* __restrict__ rows, float* __restrict__ out)
{
  __shared__ float tile[32][33];
  const int b = blockIdx.z;
  const int n0 = blockIdx.x * 32, d0 = blockIdx.y * 32;
  const int tx = threadIdx.x, ty = threadIdx.y;
#pragma unroll
  for (int i = 0; i < 4; i++) {
    const int n = n0 + ty + i * 8;
    tile[ty + i * 8][tx] = rows[((size_t)b * NN + n) * DIM + d0 + tx];
  }
  __syncthreads();
#pragma unroll
  for (int i = 0; i < 4; i++) {
    const int d = d0 + ty + i * 8;
    out[(size_t)b * DIM * NN + (size_t)d * NN + n0 + tx] = tile[tx][ty + i * 8];
  }
}

// ---------------- W (K,N) f32 -> WT (N,K) bf16 ------------------------------
__global__ __launch_bounds__(256) void wtrans_kernel(
    const float* __restrict__ W, __hip_bfloat16* __restrict__ WT, int K, int N)
{
  __shared__ float tile[32][33];
  const int n0 = blockIdx.x * 32, k0 = blockIdx.y * 32;
  const int tx = threadIdx.x, ty = threadIdx.y;   // 32 x 8
#pragma unroll
  for (int i = 0; i < 4; i++)
    tile[ty + i * 8][tx] = W[(size_t)(k0 + ty + i * 8) * N + n0 + tx];
  __syncthreads();
#pragma unroll
  for (int i = 0; i < 4; i++)
    WT[(size_t)(n0 + ty + i * 8) * K + k0 + tx] =
        __float2bfloat16(tile[tx][ty + i * 8]);
}

// ---------------- MFMA GEMM: C = act(A @ BT^T + bias) (+resid) --------------
// A [M][*lda*] bf16 rm (K used cols), BT [N][K] bf16 rm, bias f32.
// 256 thr = 4 waves (2x2), 128x128 tile, BK=32, 16x16x32 MFMA.
#define LDP 40   // LDS row pitch in bf16 (pad 32 -> 40, conflict-free)
template<bool RELU, bool RES, bool OUTBF>
__global__ __launch_bounds__(256) void mfma_gemm_kernel(
    const __hip_bfloat16* __restrict__ A, const __hip_bfloat16* __restrict__ BT,
    const float* __restrict__ bias, const float* __restrict__ resid,
    float* __restrict__ outf, __hip_bfloat16* __restrict__ outb,
    int K, int Nc, int lda)
{
  __shared__ __align__(16) short As[128 * LDP];
  __shared__ __align__(16) short Bs[128 * LDP];
  const int tid = threadIdx.x;
  const int lane = tid & 63, wid = tid >> 6;
  const int wm = wid >> 1, wn = wid & 1;
  const size_t rowBase = (size_t)blockIdx.y * 128;
  const size_t colBase = (size_t)blockIdx.x * 128;
  f4_t acc[4][4] = {};
  const int lr = lane & 15, lg = lane >> 4;     // frag row/col, k-group
  for (int k0 = 0; k0 < K; k0 += 32) {
#pragma unroll
    for (int l = 0; l < 2; l++) {
      const int c = tid + l * 256;
      const int r = c >> 2, ko = (c & 3) * 8;
      *(uint4*)&As[r * LDP + ko] =
          *(const uint4*)&A[(rowBase + r) * (size_t)lda + k0 + ko];
      *(uint4*)&Bs[r * LDP + ko] =
          *(const uint4*)&BT[(colBase + r) * (size_t)K + k0 + ko];
    }
    __syncthreads();
    bf8_t af[4], bfr[4];
#pragma unroll
    for (int mi = 0; mi < 4; mi++)
      af[mi] = *(const bf8_t*)&As[(wm * 64 + mi * 16 + lr) * LDP + lg * 8];
#pragma unroll
    for (int ni = 0; ni < 4; ni++)
      bfr[ni] = *(const bf8_t*)&Bs[(wn * 64 + ni * 16 + lr) * LDP + lg * 8];
#pragma unroll
    for (int mi = 0; mi < 4; mi++)
#pragma unroll
      for (int ni = 0; ni < 4; ni++)
        acc[mi][ni] = __builtin_amdgcn_mfma_f32_16x16x32_bf16(
            af[mi], bfr[ni], acc[mi][ni], 0, 0, 0);
    __syncthreads();
  }
#pragma unroll
  for (int ni = 0; ni < 4; ni++) {
    const size_t col = colBase + wn * 64 + ni * 16 + lr;
    const float bv = bias[col];
#pragma unroll
    for (int mi = 0; mi < 4; mi++) {
#pragma unroll
      for (int r = 0; r < 4; r++) {
        const size_t row = rowBase + wm * 64 + mi * 16 + lg * 4 + r;
        float v = acc[mi][ni][r] + bv;
        if (RELU) v = fmaxf(v, 0.0f);
        if (RES) v += resid[row * Nc + col];
        if (OUTBF) outb[row * Nc + col] = __float2bfloat16(v);
        else       outf[row * Nc + col] = v;
      }
    }
  }
}

// ------- fused k1|v1 MFMA GEMM w/ bilinear-sampled A (shared A staging) -----
// BT = [2*DIM][DIM] (Wk1^T rows 0..383, Wv1^T rows 384..767); Nc = 768.
// Per-block bias select: colBase<DIM -> biasK else biasV. Output ReLU bf16.
__global__ __launch_bounds__(256) void mfma_gemm_sampled_kv(
    const float* __restrict__ kvrows, const int* __restrict__ y0buf,
    const float* __restrict__ wbuf, const __hip_bfloat16* __restrict__ BT,
    const float* __restrict__ biasK, const float* __restrict__ biasV,
    __hip_bfloat16* __restrict__ outb, int byBase)
{
  const int K = DIM, Nc = 2 * DIM;
  __shared__ __align__(16) short As[128 * LDP];
  __shared__ __align__(16) short Bs[128 * LDP];
  const int tid = threadIdx.x;
  const int lane = tid & 63, wid = tid >> 6;
  const int wm = wid >> 1, wn = wid & 1;
  const int byG = blockIdx.y + byBase;
  const int b = byG >> 2, kk = byG & 3;
  const size_t rowBase = (size_t)blockIdx.y * 128;   // chunk-local out row
  const size_t colBase = (size_t)blockIdx.x * 128;
  f4_t acc[4][4] = {};
  const int lr = lane & 15, lg = lane >> 4;
  for (int k0 = 0; k0 < K; k0 += 32) {
#pragma unroll
    for (int l = 0; l < 2; l++) {
      const int c = tid + l * 256;
      const int r = c >> 2, ko = (c & 3) * 8;
      const int d = k0 + ko;
      const int g = d / DG;
      const int sidx = (((b * NG + g) * NKK) + kk) * NN + r;
      const int y0 = y0buf[sidx];
      const float w = wbuf[sidx];
      float4 a0 = make_float4(0.f, 0.f, 0.f, 0.f), a1 = a0, b0 = a0, b1 = a0;
      if (y0 >= 0) {
        const float* p = &kvrows[((size_t)b * NN + y0) * DIM + d];
        a0 = *(const float4*)p; a1 = *(const float4*)(p + 4);
      }
      if (y0 < NN - 1) {
        const float* p = &kvrows[((size_t)b * NN + y0 + 1) * DIM + d];
        b0 = *(const float4*)p; b1 = *(const float4*)(p + 4);
      }
      const float w0 = 1.0f - w;
      short sv[8];
      sv[0] = f2bf(a0.x * w0 + b0.x * w); sv[1] = f2bf(a0.y * w0 + b0.y * w);
      sv[2] = f2bf(a0.z * w0 + b0.z * w); sv[3] = f2bf(a0.w * w0 + b0.w * w);
      sv[4] = f2bf(a1.x * w0 + b1.x * w); sv[5] = f2bf(a1.y * w0 + b1.y * w);
      sv[6] = f2bf(a1.z * w0 + b1.z * w); sv[7] = f2bf(a1.w * w0 + b1.w * w);
      *(uint4*)&As[r * LDP + ko] = *(const uint4*)&sv[0];
      *(uint4*)&Bs[r * LDP + ko] =
          *(const uint4*)&BT[(colBase + r) * (size_t)K + k0 + ko];
    }
    __syncthreads();
    bf8_t af[4], bfr[4];
#pragma unroll
    for (int mi = 0; mi < 4; mi++)
      af[mi] = *(const bf8_t*)&As[(wm * 64 + mi * 16 + lr) * LDP + lg * 8];
#pragma unroll
    for (int ni = 0; ni < 4; ni++)
      bfr[ni] = *(const bf8_t*)&Bs[(wn * 64 + ni * 16 + lr) * LDP + lg * 8];
#pragma unroll
    for (int mi = 0; mi < 4; mi++)
#pragma unroll
      for (int ni = 0; ni < 4; ni++)
        acc[mi][ni] = __builtin_amdgcn_mfma_f32_16x16x32_bf16(
            af[mi], bfr[ni], acc[mi][ni], 0, 0, 0);
    __syncthreads();
  }
  const float* bp = (colBase < (size_t)DIM) ? biasK : biasV;
  const int cofs = (colBase < (size_t)DIM) ? 0 : DIM;
#pragma unroll
  for (int ni = 0; ni < 4; ni++) {
    const size_t col = colBase + wn * 64 + ni * 16 + lr;
    const float bv = bp[col - cofs];
#pragma unroll
    for (int mi = 0; mi < 4; mi++) {
#pragma unroll
      for (int r = 0; r < 4; r++) {
        const size_t row = rowBase + wm * 64 + mi * 16 + lg * 4 + r;
        const float v = fmaxf(acc[mi][ni][r] + bv, 0.0f);   // ReLU
        outb[row * Nc + col] = __float2bfloat16(v);
      }
    }
  }
}

// ------- offsets v3: channel-per-lane, n-tiled by 16 for occupancy ----------
// Block = (b,g) x n-tile: 192 threads (3 waves), lane owns channel c.
// Same arithmetic order as validated offset2 (tap order, 3-way wave-partial).
__global__ __launch_bounds__(192) void offset3_kernel(
    const float* __restrict__ qproj, const float* __restrict__ dw_w,
    const float* __restrict__ dw_b, const float* __restrict__ pw_w,
    int* __restrict__ y0buf, float* __restrict__ wbuf)
{
  const int bg = blockIdx.x;               // b*NG + g
  const int n0 = blockIdx.y * 16;          // n-tile base
  const int b = bg >> 1, g = bg & 1;
  const int t = threadIdx.x;               // 0..191 (= channel c)
  const int lane = t & 63, wv = t >> 6;
  __shared__ float part[16][3][4];         // per-n, per-wave, per-k partials

  const float* qp = qproj + (size_t)b * NN * DIM + g * DG + t;  // stride DIM
  float dwc[KSZ];
#pragma unroll
  for (int tap = 0; tap < KSZ; ++tap) dwc[tap] = dw_w[t * KSZ + tap];
  const float db = dw_b[t];
  const float pw0 = pw_w[0 * DG + t], pw1 = pw_w[1 * DG + t];
  const float pw2 = pw_w[2 * DG + t], pw3 = pw_w[3 * DG + t];

  float x[16 + KSZ - 1];                   // window n0-3 .. n0+18
#pragma unroll
  for (int j = 0; j < 16 + KSZ - 1; ++j) {
    const int np = n0 - 3 + j;
    x[j] = ((unsigned)np < (unsigned)NN) ? qp[(size_t)np * DIM] : 0.f;
  }
#pragma unroll
  for (int j = 0; j < 16; ++j) {
    float y = db;
#pragma unroll
    for (int i = 0; i < KSZ; ++i) y = fmaf(x[j + i], dwc[i], y);
    const float gl = geluf(y);
    float p0 = pw0 * gl, p1 = pw1 * gl, p2 = pw2 * gl, p3 = pw3 * gl;
#pragma unroll
    for (int o = 32; o; o >>= 1) {
      p0 += __shfl_down(p0, o);
      p1 += __shfl_down(p1, o);
      p2 += __shfl_down(p2, o);
      p3 += __shfl_down(p3, o);
    }
    if (lane == 0) {
      part[j][wv][0] = p0; part[j][wv][1] = p1;
      part[j][wv][2] = p2; part[j][wv][3] = p3;
    }
  }
  __syncthreads();
  if (t < 64) {                            // 16 n x 4 k work items
    const int j = t >> 2, kk = t & 3;
    const int n = n0 + j;
    const float acc = part[j][0][kk] + part[j][1][kk] + part[j][2][kk];
    const float off = tanhf(acc) * 4.0f;
    const float vgrid = (float)n + off;
    float vg = 2.0f * vgrid / (float)(NN - 1) - 1.0f;
    vg = fminf(fmaxf(vg, -1.0f), 1.0f);
    const float iy = ((vg + 1.0f) * (float)NN - 1.0f) * 0.5f;
    const float y0f = floorf(iy);
    const int idx = (bg * NKK + kk) * NN + n;
    y0buf[idx] = (int)y0f;
    wbuf[idx] = iy - y0f;
  }
}

// ------- per-position 4-key attention; adds result into qrows (residual) ----
__global__ __launch_bounds__(128) void attn_kernel(
    const float* __restrict__ qproj, const float* __restrict__ k_ch,
    const float* __restrict__ v_ch, const float* __restrict__ attn_scale,
    float* __restrict__ qrows, int bBase)
{
  const int bid = blockIdx.x;
  const int h = bid & 3;
  const int bnl = bid >> 2;                   // local b*N + n
  const int bl = bnl >> 7;
  const int n = bnl & 127;
  const size_t bn = ((size_t)(bBase + bl)) * NN + n;   // global row
  const int t = threadIdx.x;
  const int lane = t & 63, wid = t >> 6;
  __shared__ float red[2][4];
  __shared__ float simsh[4];
  float qv = 0.f;
  if (t < DHH)
    qv = qproj[bn * DIM + h * DHH + t] * 0.10206207261596577f;  // 96^-0.5
#pragma unroll
  for (int kk = 0; kk < NKK; kk++) {
    float pv = 0.f;
    if (t < DHH)
      pv = qv * k_ch[(((size_t)bl * NKK + kk) * NN + n) * DIM + h * DHH + t];
#pragma unroll
    for (int o = 32; o; o >>= 1) pv += __shfl_down(pv, o);
    if (lane == 0) red[wid][kk] = pv;
  }
  __syncthreads();
  if (t == 0) {
#pragma unroll
    for (int kk = 0; kk < NKK; kk++)
      simsh[kk] = (red[0][kk] + red[1][kk]) * 0.08838834764831845f; // 128^-0.5
  }
  __syncthreads();
  const float s0 = simsh[0], s1 = simsh[1], s2 = simsh[2], s3 = simsh[3];
  const float m = fmaxf(fmaxf(s0, s1), fmaxf(s2, s3));
  const float sc = attn_scale[0];
  const float e0 = expf((s0 - m) * sc), e1 = expf((s1 - m) * sc);
  const float e2 = expf((s2 - m) * sc), e3 = expf((s3 - m) * sc);
  const float inv = 1.0f / (e0 + e1 + e2 + e3);
  if (t < DHH) {
    const size_t vb = ((size_t)bl * NKK * NN + n) * DIM + h * DHH + t;
    const size_t stride = (size_t)NN * DIM;
    float o = e0 * inv * v_ch[vb];
    o += e1 * inv * v_ch[vb + stride];
    o += e2 * inv * v_ch[vb + 2 * stride];
    o += e3 * inv * v_ch[vb + 3 * stride];
    const size_t oi = bn * DIM + h * DHH + t;
    qrows[oi] = qrows[oi] + o;      // fused residual: q_pe + attn_out
  }
}

extern "C" void kernel_launch(void* const* d_in, const int* in_sizes, int n_in,
                              void* d_out, int out_size, void* d_ws, size_t ws_size,
                              hipStream_t stream)
{
  const float* q_raw    = (const float*)d_in[0];
  const float* kv_raw   = (const float*)d_in[1];
  const float* emb_q    = (const float*)d_in[2];
  const float* ln_pq_g  = (const float*)d_in[3];
  const float* ln_pq_b  = (const float*)d_in[4];
  const float* emb_kv   = (const float*)d_in[5];
  const float* ln_pkv_g = (const float*)d_in[6];
  const float* ln_pkv_b = (const float*)d_in[7];
  const float* Wq1 = (const float*)d_in[8];   const float* bq1 = (const float*)d_in[9];
  const float* Wq2 = (const float*)d_in[10];  const float* bq2 = (const float*)d_in[11];
  const float* Wk1 = (const float*)d_in[12];  const float* bk1 = (const float*)d_in[13];
  const float* Wk2 = (const float*)d_in[14];  const float* bk2 = (const float*)d_in[15];
  const float* Wv1 = (const float*)d_in[16];  const float* bv1 = (const float*)d_in[17];
  const float* Wv2 = (const float*)d_in[18];  const float* bv2 = (const float*)d_in[19];
  const float* dw_w = (const float*)d_in[20]; const float* dw_b = (const float*)d_in[21];
  const float* pw_w = (const float*)d_in[22];
  const float* ln1_g = (const float*)d_in[23]; const float* ln1_b = (const float*)d_in[24];
  const float* ln2_g = (const float*)d_in[25]; const float* ln2_b = (const float*)d_in[26];
  const float* Wf1 = (const float*)d_in[27];  const float* bf1 = (const float*)d_in[28];
  const float* Wf2 = (const float*)d_in[29];  const float* bf2 = (const float*)d_in[30];
  const float* attn_scale = (const float*)d_in[31];
  float* out = (float*)d_out;

  // ---- dynamic workspace config -------------------------------------------
  // chunk-region floats: max( S (q-MLP), ROWS*1152 (k/v: hid_kv+k_ch+v_ch),
  //                           S/2 + 33.55M/NFQ (FFN) )
  const size_t S = (size_t)BB * NN * DIM;            // 12,582,912
  const size_t TAILF = 4 * 73728 + 147456 + 2 * 393216 + 2 * (size_t)NN * DIM
                     + 2 * (size_t)BB * NG * NKK * NN;
  int NCH = 16, NFQ = 8;   // fallback: ~200 MB total (< 229 MB proven-safe)
  {
    const int cand[5][2] = {{2, 1}, {4, 1}, {8, 2}, {16, 4}, {16, 8}};
    for (int i = 0; i < 5; i++) {
      const size_t rows = (size_t)(BB / cand[i][0]) * NKK * NN;
      size_t ch = S;
      const size_t pb = rows * 1152;
      const size_t pc = S / 2 + (size_t)33554432 / cand[i][1];
      if (pb > ch) ch = pb;
      if (pc > ch) ch = pc;
      const size_t totB = (3 * S + ch + TAILF) * 4;
      if (totB <= ws_size) { NCH = cand[i][0]; NFQ = cand[i][1]; break; }
    }
  }
  const int MQ = BB * NN;                      // 32768
  const int B_PER_CH = BB / NCH;
  const int BY_PER_CH = B_PER_CH * NKK;
  const int ROWS_PER_CH = BY_PER_CH * NN;      // = 131072/NCH
  const int FROWS = MQ / NFQ;
  size_t CHSZ = S;
  {
    const size_t pb = (size_t)ROWS_PER_CH * 1152;
    const size_t pc = S / 2 + (size_t)33554432 / NFQ;
    if (pb > CHSZ) CHSZ = pb;
    if (pc > CHSZ) CHSZ = pc;
  }

  // ---- workspace layout (floats), lifetime-aliased ----
  float* wsf = (float*)d_ws;
  float* qrows = wsf;                 // f32 residual rows; later lnout
  float* kvr   = qrows + S;           // f32 kv+pe rows; later res (ln1 out)
  float* qproj = kvr + S;             // f32 q MLP out; later res2
  float* chbase = qproj + S;          // shared chunk region (CHSZ floats)
  // phase a (q MLP):
  __hip_bfloat16* qrows_bf = (__hip_bfloat16*)chbase;
  __hip_bfloat16* scr_bf   = (__hip_bfloat16*)(chbase + S / 2);
  // phase b (k/v chunks): hid_kv bf16 [ROWS][768] | k_ch f32 | v_ch f32
  __hip_bfloat16* hidkv_bf = (__hip_bfloat16*)chbase;
  float* k_ch = chbase + (size_t)ROWS_PER_CH * DIM;   // hid_kv = ROWS*384 floats
  float* v_ch = k_ch + (size_t)ROWS_PER_CH * DIM;
  // phase c (FFN):
  __hip_bfloat16* res_bf = (__hip_bfloat16*)chbase;
  __hip_bfloat16* ffnh   = (__hip_bfloat16*)(chbase + S / 2);
  // tail: bf16 transposed weights, pe, coords
  float* p = chbase + CHSZ;
  __hip_bfloat16* wtq1  = (__hip_bfloat16*)p; p += 73728;
  __hip_bfloat16* wtq2  = (__hip_bfloat16*)p; p += 73728;
  __hip_bfloat16* wtkv1 = (__hip_bfloat16*)p; p += 147456;  // [768][384]
  __hip_bfloat16* wtk2  = (__hip_bfloat16*)p; p += 73728;
  __hip_bfloat16* wtv2  = (__hip_bfloat16*)p; p += 73728;
  __hip_bfloat16* wtf1  = (__hip_bfloat16*)p; p += 393216;
  __hip_bfloat16* wtf2  = (__hip_bfloat16*)p; p += 393216;
  float* peq  = p; p += (size_t)NN * DIM;
  float* pekv = p; p += (size_t)NN * DIM;
  int*   y0buf = (int*)p; p += (size_t)BB * NG * NKK * NN;
  float* wbuf  = p;
  float* res   = kvr;
  float* res2  = qproj;
  float* lnout = qrows;

  // 0) weight convert+transpose to bf16 (graph-safe, every call)
  wtrans_kernel<<<dim3(DIM/32, DIM/32), dim3(32, 8), 0, stream>>>(Wq1, wtq1, DIM, DIM);
  wtrans_kernel<<<dim3(DIM/32, DIM/32), dim3(32, 8), 0, stream>>>(Wq2, wtq2, DIM, DIM);
  wtrans_kernel<<<dim3(DIM/32, DIM/32), dim3(32, 8), 0, stream>>>(Wk1, wtkv1, DIM, DIM);
  wtrans_kernel<<<dim3(DIM/32, DIM/32), dim3(32, 8), 0, stream>>>(
      Wv1, wtkv1 + (size_t)DIM * DIM, DIM, DIM);
  wtrans_kernel<<<dim3(DIM/32, DIM/32), dim3(32, 8), 0, stream>>>(Wk2, wtk2, DIM, DIM);
  wtrans_kernel<<<dim3(DIM/32, DIM/32), dim3(32, 8), 0, stream>>>(Wv2, wtv2, DIM, DIM);
  wtrans_kernel<<<dim3(DFF/32, DIM/32), dim3(32, 8), 0, stream>>>(Wf1, wtf1, DIM, DFF);
  wtrans_kernel<<<dim3(DIM/32, DFF/32), dim3(32, 8), 0, stream>>>(Wf2, wtf2, DFF, DIM);

  // 1) positional-encoding LayerNorms
  ln_rows_kernel<false><<<dim3(NN), dim3(128), 0, stream>>>(
      emb_q, ln_pq_g, ln_pq_b, peq, nullptr);
  ln_rows_kernel<false><<<dim3(NN), dim3(128), 0, stream>>>(
      emb_kv, ln_pkv_g, ln_pkv_b, pekv, nullptr);

  // 2) transpose to rows + add pos-enc (q also emits bf16 for the MLP)
  transpose_addpe<true><<<dim3(NN/32, DIM/32, BB), dim3(32, 8), 0, stream>>>(
      q_raw, peq, qrows, qrows_bf);
  transpose_addpe<false><<<dim3(NN/32, DIM/32, BB), dim3(32, 8), 0, stream>>>(
      kv_raw, pekv, kvr, nullptr);

  // 3) q MLP (bf16 MFMA; hidden bf16, output f32)
  mfma_gemm_kernel<true, false, true><<<dim3(DIM/128, MQ/128), 256, 0, stream>>>(
      qrows_bf, wtq1, bq1, nullptr, nullptr, scr_bf, DIM, DIM, DIM);
  mfma_gemm_kernel<false, false, false><<<dim3(DIM/128, MQ/128), 256, 0, stream>>>(
      scr_bf, wtq2, bq2, nullptr, qproj, nullptr, DIM, DIM, DIM);

  // 4) offset prediction -> sampling coords (f32, channel-per-lane, n-tiled)
  offset3_kernel<<<dim3(BB * NG, NN / 16), dim3(192), 0, stream>>>(
      qproj, dw_w, dw_b, pw_w, y0buf, wbuf);

  // 5) per batch-chunk: fused k1|v1 sampled GEMM, layer-2 k/v, attention
  for (int c = 0; c < NCH; ++c) {
    const int byBase = c * BY_PER_CH;
    mfma_gemm_sampled_kv<<<dim3(2 * DIM / 128, BY_PER_CH), 256, 0, stream>>>(
        kvr, y0buf, wbuf, wtkv1, bk1, bv1, hidkv_bf, byBase);
    mfma_gemm_kernel<false, false, false><<<dim3(DIM/128, ROWS_PER_CH/128), 256, 0, stream>>>(
        hidkv_bf, wtk2, bk2, nullptr, k_ch, nullptr, DIM, DIM, 2 * DIM);
    mfma_gemm_kernel<false, false, false><<<dim3(DIM/128, ROWS_PER_CH/128), 256, 0, stream>>>(
        hidkv_bf + DIM, wtv2, bv2, nullptr, v_ch, nullptr, DIM, DIM, 2 * DIM);
    attn_kernel<<<dim3(B_PER_CH * NN * NH), 128, 0, stream>>>(
        qproj, k_ch, v_ch, attn_scale, qrows, c * B_PER_CH);
  }

  // 6) res = LN(q_pe + attn_out); also emit bf16 for FFN input
  ln_rows_kernel<true><<<dim3(MQ), dim3(128), 0, stream>>>(
      qrows, ln1_g, ln1_b, res, res_bf);

  // 7) FFN in row-chunks (bf16 MFMA), residual fused into second GEMM
  for (int q = 0; q < NFQ; ++q) {
    const size_t roff = (size_t)q * FROWS;
    mfma_gemm_kernel<true, false, true><<<dim3(DFF/128, FROWS/128), 256, 0, stream>>>(
        res_bf + roff * DIM, wtf1, bf1, nullptr, nullptr, ffnh, DIM, DFF, DIM);
    mfma_gemm_kernel<false, true, false><<<dim3(DIM/128, FROWS/128), 256, 0, stream>>>(
        ffnh, wtf2, bf2, res + roff * DIM, res2 + roff * DIM, nullptr, DFF, DIM, DFF);
  }

  // 8) final LN + transpose back to (B, DIM, N)
  ln_rows_kernel<false><<<dim3(MQ), dim3(128), 0, stream>>>(
      res2, ln2_g, ln2_b, lnout, nullptr);
  transpose_to_cf<<<dim3(NN/32, DIM/32, BB), dim3(32, 8), 0, stream>>>(
      lnout, out);
}

// Round 12
// 1143.104 us; speedup vs baseline: 4.9145x; 1.1072x over previous
//
#include <hip/hip_runtime.h>
#include <hip/hip_bf16.h>
#include <cstdint>
#include <cstddef>

#define BB   256
#define DIM  384
#define NN   128
#define NH   4
#define NG   2
#define NKK  4
#define DHH  96
#define DG   192
#define KSZ  7
#define DFF  2048

typedef __attribute__((ext_vector_type(8))) short bf8_t;   // 8 bf16 (4 VGPR)
typedef __attribute__((ext_vector_type(4))) float f4_t;    // 4 f32 acc

static __device__ __forceinline__ float geluf(float x) {
  return 0.5f * x * (1.0f + erff(x * 0.70710678118654752440f));
}
static __device__ __forceinline__ short f2bf(float f) {
  union { __hip_bfloat16 h; short s; } u;
  u.h = __float2bfloat16(f);
  return u.s;
}

// XCD-aware bijective block remap (m204): consecutive physical ids round-robin
// XCDs; this gives each XCD a contiguous logical range -> A-panel L2 reuse.
static __device__ __forceinline__ void xcd_swizzle(int& bx, int& by) {
  const int gx = gridDim.x;
  const int nwg = gx * gridDim.y;
  const int flat = by * gx + bx;
  const int q = nwg >> 3, r = nwg & 7;
  const int xcd = flat & 7, idx = flat >> 3;
  const int logical =
      (xcd < r ? xcd * (q + 1) : r * (q + 1) + (xcd - r) * q) + idx;
  bx = logical % gx;
  by = logical / gx;
}

// ---------------- LayerNorm rows of 384; optional secondary bf16 output -----
template<bool WB>
__global__ __launch_bounds__(128) void ln_rows_kernel(
    const float* __restrict__ X,
    const float* __restrict__ gam, const float* __restrict__ bet,
    float* __restrict__ out, __hip_bfloat16* __restrict__ out2)
{
  const int row = blockIdx.x;
  const int t = threadIdx.x;
  const size_t base = (size_t)row * DIM;
  float x0 = X[base + t], x1 = X[base + t + 128], x2 = X[base + t + 256];
  __shared__ float ws[2];
  float s = x0 + x1 + x2;
#pragma unroll
  for (int o = 32; o; o >>= 1) s += __shfl_down(s, o);
  if ((t & 63) == 0) ws[t >> 6] = s;
  __syncthreads();
  const float m = (ws[0] + ws[1]) * (1.0f / DIM);
  __syncthreads();
  const float d0 = x0 - m, d1 = x1 - m, d2 = x2 - m;
  float v = d0 * d0 + d1 * d1 + d2 * d2;
#pragma unroll
  for (int o = 32; o; o >>= 1) v += __shfl_down(v, o);
  if ((t & 63) == 0) ws[t >> 6] = v;
  __syncthreads();
  const float var = (ws[0] + ws[1]) * (1.0f / DIM);
  const float rs = rsqrtf(var + 1e-5f);
  const float o0 = d0 * rs * gam[t]       + bet[t];
  const float o1 = d1 * rs * gam[t + 128] + bet[t + 128];
  const float o2 = d2 * rs * gam[t + 256] + bet[t + 256];
  out[base + t] = o0; out[base + t + 128] = o1; out[base + t + 256] = o2;
  if (WB) {
    out2[base + t]       = __float2bfloat16(o0);
    out2[base + t + 128] = __float2bfloat16(o1);
    out2[base + t + 256] = __float2bfloat16(o2);
  }
}

// ---------------- (B,DIM,N) + pe(N,DIM) -> rows (B,N,DIM) (+bf16 copy) ------
template<bool WB>
__global__ __launch_bounds__(256) void transpose_addpe(
    const float* __restrict__ X, const float* __restrict__ pe,
    float* __restrict__ out, __hip_bfloat16* __restrict__ outb)
{
  __shared__ float tile[32][33];
  const int b = blockIdx.z;
  const int n0 = blockIdx.x * 32, d0 = blockIdx.y * 32;
  const int tx = threadIdx.x, ty = threadIdx.y;   // 32 x 8
#pragma unroll
  for (int i = 0; i < 4; i++) {
    const int d = d0 + ty + i * 8;
    tile[ty + i * 8][tx] = X[(size_t)b * DIM * NN + (size_t)d * NN + n0 + tx];
  }
  __syncthreads();
#pragma unroll
  for (int i = 0; i < 4; i++) {
    const int n = n0 + ty + i * 8;
    const int d = d0 + tx;
    const float v = tile[tx][ty + i * 8] + pe[n * DIM + d];
    out[((size_t)b * NN + n) * DIM + d] = v;
    if (WB) outb[((size_t)b * NN + n) * DIM + d] = __float2bfloat16(v);
  }
}

// ---------------- rows (B,N,DIM) -> (B,DIM,N) -------------------------------
__global__ __launch_bounds__(256) void transpose_to_cf(
    const float* __restrict__ rows, float* __restrict__ out)
{
  __shared__ float tile[32][33];
  const int b = blockIdx.z;
  const int n0 = blockIdx.x * 32, d0 = blockIdx.y * 32;
  const int tx = threadIdx.x, ty = threadIdx.y;
#pragma unroll
  for (int i = 0; i < 4; i++) {
    const int n = n0 + ty + i * 8;
    tile[ty + i * 8][tx] = rows[((size_t)b * NN + n) * DIM + d0 + tx];
  }
  __syncthreads();
#pragma unroll
  for (int i = 0; i < 4; i++) {
    const int d = d0 + ty + i * 8;
    out[(size_t)b * DIM * NN + (size_t)d * NN + n0 + tx] = tile[tx][ty + i * 8];
  }
}

// ---------------- W (K,N) f32 -> WT (N,K) bf16 ------------------------------
__global__ __launch_bounds__(256) void wtrans_kernel(
    const float* __restrict__ W, __hip_bfloat16* __restrict__ WT, int K, int N)
{
  __shared__ float tile[32][33];
  const int n0 = blockIdx.x * 32, k0 = blockIdx.y * 32;
  const int tx = threadIdx.x, ty = threadIdx.y;   // 32 x 8
#pragma unroll
  for (int i = 0; i < 4; i++)
    tile[ty + i * 8][tx] = W[(size_t)(k0 + ty + i * 8) * N + n0 + tx];
  __syncthreads();
#pragma unroll
  for (int i = 0; i < 4; i++)
    WT[(size_t)(n0 + ty + i * 8) * K + k0 + tx] =
        __float2bfloat16(tile[tx][ty + i * 8]);
}

// ---------------- concat two bias vectors [n]+[n] -> [2n] -------------------
__global__ __launch_bounds__(256) void concat_bias_kernel(
    const float* __restrict__ a, const float* __restrict__ b,
    float* __restrict__ o, int n)
{
  const int i = blockIdx.x * 256 + threadIdx.x;
  if (i < 2 * n) o[i] = (i < n) ? a[i] : b[i - n];
}

// ---------------- MFMA GEMM: C = act(A @ BT^T + bias) (+resid) --------------
// A [M][*lda*] bf16 rm (K used cols), BT [N][K] bf16 rm, bias f32.
// 256 thr = 4 waves (2x2), 128x128 tile, BK=32, 16x16x32 MFMA. XCD-swizzled.
#define LDP 40   // LDS row pitch in bf16 (pad 32 -> 40; only free 2-way alias)
template<bool RELU, bool RES, bool OUTBF>
__global__ __launch_bounds__(256) void mfma_gemm_kernel(
    const __hip_bfloat16* __restrict__ A, const __hip_bfloat16* __restrict__ BT,
    const float* __restrict__ bias, const float* __restrict__ resid,
    float* __restrict__ outf, __hip_bfloat16* __restrict__ outb,
    int K, int Nc, int lda)
{
  __shared__ __align__(16) short As[128 * LDP];
  __shared__ __align__(16) short Bs[128 * LDP];
  const int tid = threadIdx.x;
  const int lane = tid & 63, wid = tid >> 6;
  const int wm = wid >> 1, wn = wid & 1;
  int bx = blockIdx.x, by = blockIdx.y;
  xcd_swizzle(bx, by);
  const size_t rowBase = (size_t)by * 128;
  const size_t colBase = (size_t)bx * 128;
  f4_t acc[4][4] = {};
  const int lr = lane & 15, lg = lane >> 4;     // frag row/col, k-group
  for (int k0 = 0; k0 < K; k0 += 32) {
#pragma unroll
    for (int l = 0; l < 2; l++) {
      const int c = tid + l * 256;
      const int r = c >> 2, ko = (c & 3) * 8;
      *(uint4*)&As[r * LDP + ko] =
          *(const uint4*)&A[(rowBase + r) * (size_t)lda + k0 + ko];
      *(uint4*)&Bs[r * LDP + ko] =
          *(const uint4*)&BT[(colBase + r) * (size_t)K + k0 + ko];
    }
    __syncthreads();
    bf8_t af[4], bfr[4];
#pragma unroll
    for (int mi = 0; mi < 4; mi++)
      af[mi] = *(const bf8_t*)&As[(wm * 64 + mi * 16 + lr) * LDP + lg * 8];
#pragma unroll
    for (int ni = 0; ni < 4; ni++)
      bfr[ni] = *(const bf8_t*)&Bs[(wn * 64 + ni * 16 + lr) * LDP + lg * 8];
#pragma unroll
    for (int mi = 0; mi < 4; mi++)
#pragma unroll
      for (int ni = 0; ni < 4; ni++)
        acc[mi][ni] = __builtin_amdgcn_mfma_f32_16x16x32_bf16(
            af[mi], bfr[ni], acc[mi][ni], 0, 0, 0);
    __syncthreads();
  }
#pragma unroll
  for (int ni = 0; ni < 4; ni++) {
    const size_t col = colBase + wn * 64 + ni * 16 + lr;
    const float bv = bias[col];
#pragma unroll
    for (int mi = 0; mi < 4; mi++) {
#pragma unroll
      for (int r = 0; r < 4; r++) {
        const size_t row = rowBase + wm * 64 + mi * 16 + lg * 4 + r;
        float v = acc[mi][ni][r] + bv;
        if (RELU) v = fmaxf(v, 0.0f);
        if (RES) v += resid[row * Nc + col];
        if (OUTBF) outb[row * Nc + col] = __float2bfloat16(v);
        else       outf[row * Nc + col] = v;
      }
    }
  }
}

// ------- merged k2|v2 GEMM: one dispatch, by-range selects half -------------
// A = hidkv [rows][768] bf16; half 0: cols 0..383 @ Wk2 -> outK; half 1:
// cols 384..767 @ Wv2 -> outV. K=Nc=384, lda=768.
__global__ __launch_bounds__(256) void mfma_gemm_kv2(
    const __hip_bfloat16* __restrict__ hidkv,
    const __hip_bfloat16* __restrict__ BTk, const __hip_bfloat16* __restrict__ BTv,
    const float* __restrict__ biasK, const float* __restrict__ biasV,
    float* __restrict__ outK, float* __restrict__ outV)
{
  const int K = DIM, Nc = DIM, lda = 2 * DIM;
  __shared__ __align__(16) short As[128 * LDP];
  __shared__ __align__(16) short Bs[128 * LDP];
  const int tid = threadIdx.x;
  const int lane = tid & 63, wid = tid >> 6;
  const int wm = wid >> 1, wn = wid & 1;
  int bx = blockIdx.x, by = blockIdx.y;
  xcd_swizzle(bx, by);
  const int nbyh = gridDim.y >> 1;
  const int half = (by >= nbyh) ? 1 : 0;
  const int byl = by - half * nbyh;
  const __hip_bfloat16* A = hidkv + half * DIM;
  const __hip_bfloat16* BT = half ? BTv : BTk;
  const float* bias = half ? biasV : biasK;
  float* outf = half ? outV : outK;
  const size_t rowBase = (size_t)byl * 128;
  const size_t colBase = (size_t)bx * 128;
  f4_t acc[4][4] = {};
  const int lr = lane & 15, lg = lane >> 4;
  for (int k0 = 0; k0 < K; k0 += 32) {
#pragma unroll
    for (int l = 0; l < 2; l++) {
      const int c = tid + l * 256;
      const int r = c >> 2, ko = (c & 3) * 8;
      *(uint4*)&As[r * LDP + ko] =
          *(const uint4*)&A[(rowBase + r) * (size_t)lda + k0 + ko];
      *(uint4*)&Bs[r * LDP + ko] =
          *(const uint4*)&BT[(colBase + r) * (size_t)K + k0 + ko];
    }
    __syncthreads();
    bf8_t af[4], bfr[4];
#pragma unroll
    for (int mi = 0; mi < 4; mi++)
      af[mi] = *(const bf8_t*)&As[(wm * 64 + mi * 16 + lr) * LDP + lg * 8];
#pragma unroll
    for (int ni = 0; ni < 4; ni++)
      bfr[ni] = *(const bf8_t*)&Bs[(wn * 64 + ni * 16 + lr) * LDP + lg * 8];
#pragma unroll
    for (int mi = 0; mi < 4; mi++)
#pragma unroll
      for (int ni = 0; ni < 4; ni++)
        acc[mi][ni] = __builtin_amdgcn_mfma_f32_16x16x32_bf16(
            af[mi], bfr[ni], acc[mi][ni], 0, 0, 0);
    __syncthreads();
  }
#pragma unroll
  for (int ni = 0; ni < 4; ni++) {
    const size_t col = colBase + wn * 64 + ni * 16 + lr;
    const float bv = bias[col];
#pragma unroll
    for (int mi = 0; mi < 4; mi++) {
#pragma unroll
      for (int r = 0; r < 4; r++) {
        const size_t row = rowBase + wm * 64 + mi * 16 + lg * 4 + r;
        outf[row * Nc + col] = acc[mi][ni][r] + bv;
      }
    }
  }
}

// ------- bilinear-sample kv rows once -> bf16 A [rows][384] -----------------
// Thread handles 8 cols (16B store). Same arithmetic as r10's in-GEMM path.
__global__ __launch_bounds__(256) void sample_rows_kernel(
    const float* __restrict__ kvrows, const int* __restrict__ y0buf,
    const float* __restrict__ wbuf, __hip_bfloat16* __restrict__ outb,
    int byBase)
{
  const int gid = blockIdx.x * 256 + threadIdx.x;   // < rows*48
  const int rowl = gid / 48, c8 = gid - rowl * 48;
  const int d = c8 * 8;
  const int n = rowl & (NN - 1);
  const int byG = byBase + (rowl >> 7);
  const int b = byG >> 2, kk = byG & 3;
  const int g = d / DG;
  const int sidx = (((b * NG + g) * NKK) + kk) * NN + n;
  const int y0 = y0buf[sidx];
  const float w = wbuf[sidx];
  float4 a0 = make_float4(0.f, 0.f, 0.f, 0.f), a1 = a0, b0 = a0, b1 = a0;
  if (y0 >= 0) {
    const float* p = &kvrows[((size_t)b * NN + y0) * DIM + d];
    a0 = *(const float4*)p; a1 = *(const float4*)(p + 4);
  }
  if (y0 < NN - 1) {
    const float* p = &kvrows[((size_t)b * NN + y0 + 1) * DIM + d];
    b0 = *(const float4*)p; b1 = *(const float4*)(p + 4);
  }
  const float w0 = 1.0f - w;
  short sv[8];
  sv[0] = f2bf(a0.x * w0 + b0.x * w); sv[1] = f2bf(a0.y * w0 + b0.y * w);
  sv[2] = f2bf(a0.z * w0 + b0.z * w); sv[3] = f2bf(a0.w * w0 + b0.w * w);
  sv[4] = f2bf(a1.x * w0 + b1.x * w); sv[5] = f2bf(a1.y * w0 + b1.y * w);
  sv[6] = f2bf(a1.z * w0 + b1.z * w); sv[7] = f2bf(a1.w * w0 + b1.w * w);
  *(uint4*)&outb[(size_t)rowl * DIM + d] = *(const uint4*)&sv[0];
}

// ------- offsets v3: channel-per-lane, n-tiled by 16 for occupancy ----------
__global__ __launch_bounds__(192) void offset3_kernel(
    const float* __restrict__ qproj, const float* __restrict__ dw_w,
    const float* __restrict__ dw_b, const float* __restrict__ pw_w,
    int* __restrict__ y0buf, float* __restrict__ wbuf)
{
  const int bg = blockIdx.x;               // b*NG + g
  const int n0 = blockIdx.y * 16;          // n-tile base
  const int b = bg >> 1, g = bg & 1;
  const int t = threadIdx.x;               // 0..191 (= channel c)
  const int lane = t & 63, wv = t >> 6;
  __shared__ float part[16][3][4];

  const float* qp = qproj + (size_t)b * NN * DIM + g * DG + t;  // stride DIM
  float dwc[KSZ];
#pragma unroll
  for (int tap = 0; tap < KSZ; ++tap) dwc[tap] = dw_w[t * KSZ + tap];
  const float db = dw_b[t];
  const float pw0 = pw_w[0 * DG + t], pw1 = pw_w[1 * DG + t];
  const float pw2 = pw_w[2 * DG + t], pw3 = pw_w[3 * DG + t];

  float x[16 + KSZ - 1];                   // window n0-3 .. n0+18
#pragma unroll
  for (int j = 0; j < 16 + KSZ - 1; ++j) {
    const int np = n0 - 3 + j;
    x[j] = ((unsigned)np < (unsigned)NN) ? qp[(size_t)np * DIM] : 0.f;
  }
#pragma unroll
  for (int j = 0; j < 16; ++j) {
    float y = db;
#pragma unroll
    for (int i = 0; i < KSZ; ++i) y = fmaf(x[j + i], dwc[i], y);
    const float gl = geluf(y);
    float p0 = pw0 * gl, p1 = pw1 * gl, p2 = pw2 * gl, p3 = pw3 * gl;
#pragma unroll
    for (int o = 32; o; o >>= 1) {
      p0 += __shfl_down(p0, o);
      p1 += __shfl_down(p1, o);
      p2 += __shfl_down(p2, o);
      p3 += __shfl_down(p3, o);
    }
    if (lane == 0) {
      part[j][wv][0] = p0; part[j][wv][1] = p1;
      part[j][wv][2] = p2; part[j][wv][3] = p3;
    }
  }
  __syncthreads();
  if (t < 64) {                            // 16 n x 4 k work items
    const int j = t >> 2, kk = t & 3;
    const int n = n0 + j;
    const float acc = part[j][0][kk] + part[j][1][kk] + part[j][2][kk];
    const float off = tanhf(acc) * 4.0f;
    const float vgrid = (float)n + off;
    float vg = 2.0f * vgrid / (float)(NN - 1) - 1.0f;
    vg = fminf(fmaxf(vg, -1.0f), 1.0f);
    const float iy = ((vg + 1.0f) * (float)NN - 1.0f) * 0.5f;
    const float y0f = floorf(iy);
    const int idx = (bg * NKK + kk) * NN + n;
    y0buf[idx] = (int)y0f;
    wbuf[idx] = iy - y0f;
  }
}

// ------- per-position 4-key attention; adds result into qrows (residual) ----
__global__ __launch_bounds__(128) void attn_kernel(
    const float* __restrict__ qproj, const float* __restrict__ k_ch,
    const float* __restrict__ v_ch, const float* __restrict__ attn_scale,
    float* __restrict__ qrows, int bBase)
{
  const int bid = blockIdx.x;
  const int h = bid & 3;
  const int bnl = bid >> 2;                   // local b*N + n
  const int bl = bnl >> 7;
  const int n = bnl & 127;
  const size_t bn = ((size_t)(bBase + bl)) * NN + n;   // global row
  const int t = threadIdx.x;
  const int lane = t & 63, wid = t >> 6;
  __shared__ float red[2][4];
  __shared__ float simsh[4];
  float qv = 0.f;
  if (t < DHH)
    qv = qproj[bn * DIM + h * DHH + t] * 0.10206207261596577f;  // 96^-0.5
#pragma unroll
  for (int kk = 0; kk < NKK; kk++) {
    float pv = 0.f;
    if (t < DHH)
      pv = qv * k_ch[(((size_t)bl * NKK + kk) * NN + n) * DIM + h * DHH + t];
#pragma unroll
    for (int o = 32; o; o >>= 1) pv += __shfl_down(pv, o);
    if (lane == 0) red[wid][kk] = pv;
  }
  __syncthreads();
  if (t == 0) {
#pragma unroll
    for (int kk = 0; kk < NKK; kk++)
      simsh[kk] = (red[0][kk] + red[1][kk]) * 0.08838834764831845f; // 128^-0.5
  }
  __syncthreads();
  const float s0 = simsh[0], s1 = simsh[1], s2 = simsh[2], s3 = simsh[3];
  const float m = fmaxf(fmaxf(s0, s1), fmaxf(s2, s3));
  const float sc = attn_scale[0];
  const float e0 = expf((s0 - m) * sc), e1 = expf((s1 - m) * sc);
  const float e2 = expf((s2 - m) * sc), e3 = expf((s3 - m) * sc);
  const float inv = 1.0f / (e0 + e1 + e2 + e3);
  if (t < DHH) {
    const size_t vb = ((size_t)bl * NKK * NN + n) * DIM + h * DHH + t;
    const size_t stride = (size_t)NN * DIM;
    float o = e0 * inv * v_ch[vb];
    o += e1 * inv * v_ch[vb + stride];
    o += e2 * inv * v_ch[vb + 2 * stride];
    o += e3 * inv * v_ch[vb + 3 * stride];
    const size_t oi = bn * DIM + h * DHH + t;
    qrows[oi] = qrows[oi] + o;      // fused residual: q_pe + attn_out
  }
}

extern "C" void kernel_launch(void* const* d_in, const int* in_sizes, int n_in,
                              void* d_out, int out_size, void* d_ws, size_t ws_size,
                              hipStream_t stream)
{
  const float* q_raw    = (const float*)d_in[0];
  const float* kv_raw   = (const float*)d_in[1];
  const float* emb_q    = (const float*)d_in[2];
  const float* ln_pq_g  = (const float*)d_in[3];
  const float* ln_pq_b  = (const float*)d_in[4];
  const float* emb_kv   = (const float*)d_in[5];
  const float* ln_pkv_g = (const float*)d_in[6];
  const float* ln_pkv_b = (const float*)d_in[7];
  const float* Wq1 = (const float*)d_in[8];   const float* bq1 = (const float*)d_in[9];
  const float* Wq2 = (const float*)d_in[10];  const float* bq2 = (const float*)d_in[11];
  const float* Wk1 = (const float*)d_in[12];  const float* bk1 = (const float*)d_in[13];
  const float* Wk2 = (const float*)d_in[14];  const float* bk2 = (const float*)d_in[15];
  const float* Wv1 = (const float*)d_in[16];  const float* bv1 = (const float*)d_in[17];
  const float* Wv2 = (const float*)d_in[18];  const float* bv2 = (const float*)d_in[19];
  const float* dw_w = (const float*)d_in[20]; const float* dw_b = (const float*)d_in[21];
  const float* pw_w = (const float*)d_in[22];
  const float* ln1_g = (const float*)d_in[23]; const float* ln1_b = (const float*)d_in[24];
  const float* ln2_g = (const float*)d_in[25]; const float* ln2_b = (const float*)d_in[26];
  const float* Wf1 = (const float*)d_in[27];  const float* bf1 = (const float*)d_in[28];
  const float* Wf2 = (const float*)d_in[29];  const float* bf2 = (const float*)d_in[30];
  const float* attn_scale = (const float*)d_in[31];
  float* out = (float*)d_out;

  // ---- dynamic workspace config -------------------------------------------
  // chunk-region floats: max( S (q-MLP), rows*1344 (sampA+hidkv+k_ch+v_ch),
  //                           S/2 + 33.55M/NFQ (FFN) )
  const size_t S = (size_t)BB * NN * DIM;            // 12,582,912
  const size_t TAILF = 2 * 73728 + 147456 + 2 * 73728 + 2 * 393216 + 768
                     + 2 * (size_t)NN * DIM + 2 * (size_t)BB * NG * NKK * NN;
  int NCH = 16, NFQ = 8;   // fallback ~209 MB (< 229 MB proven-safe)
  {
    const int cand[5][2] = {{2, 1}, {4, 1}, {8, 2}, {16, 4}, {16, 8}};
    for (int i = 0; i < 5; i++) {
      const size_t rows = (size_t)(BB / cand[i][0]) * NKK * NN;
      size_t ch = S;
      const size_t pb = rows * 1344;
      const size_t pc = S / 2 + (size_t)33554432 / cand[i][1];
      if (pb > ch) ch = pb;
      if (pc > ch) ch = pc;
      const size_t totB = (3 * S + ch + TAILF) * 4;
      if (totB <= ws_size) { NCH = cand[i][0]; NFQ = cand[i][1]; break; }
    }
  }
  const int MQ = BB * NN;                      // 32768
  const int B_PER_CH = BB / NCH;
  const int BY_PER_CH = B_PER_CH * NKK;
  const int ROWS_PER_CH = BY_PER_CH * NN;      // = 131072/NCH
  const int FROWS = MQ / NFQ;
  size_t CHSZ = S;
  {
    const size_t pb = (size_t)ROWS_PER_CH * 1344;
    const size_t pc = S / 2 + (size_t)33554432 / NFQ;
    if (pb > CHSZ) CHSZ = pb;
    if (pc > CHSZ) CHSZ = pc;
  }

  // ---- workspace layout (floats), lifetime-aliased ----
  float* wsf = (float*)d_ws;
  float* qrows = wsf;                 // f32 residual rows; later lnout
  float* kvr   = qrows + S;           // f32 kv+pe rows; later res (ln1 out)
  float* qproj = kvr + S;             // f32 q MLP out; later res2
  float* chbase = qproj + S;          // shared chunk region (CHSZ floats)
  // phase a (q MLP):
  __hip_bfloat16* qrows_bf = (__hip_bfloat16*)chbase;
  __hip_bfloat16* scr_bf   = (__hip_bfloat16*)(chbase + S / 2);
  // phase b (k/v chunks): sampA bf16 | hidkv bf16 | k_ch f32 | v_ch f32
  __hip_bfloat16* sampA_bf = (__hip_bfloat16*)chbase;
  __hip_bfloat16* hidkv_bf = (__hip_bfloat16*)(chbase + (size_t)ROWS_PER_CH * 192);
  float* k_ch = chbase + (size_t)ROWS_PER_CH * 576;
  float* v_ch = k_ch + (size_t)ROWS_PER_CH * DIM;
  // phase c (FFN):
  __hip_bfloat16* res_bf = (__hip_bfloat16*)chbase;
  __hip_bfloat16* ffnh   = (__hip_bfloat16*)(chbase + S / 2);
  // tail: bf16 transposed weights, concat bias, pe, coords
  float* p = chbase + CHSZ;
  __hip_bfloat16* wtq1  = (__hip_bfloat16*)p; p += 73728;
  __hip_bfloat16* wtq2  = (__hip_bfloat16*)p; p += 73728;
  __hip_bfloat16* wtkv1 = (__hip_bfloat16*)p; p += 147456;  // [768][384]
  __hip_bfloat16* wtk2  = (__hip_bfloat16*)p; p += 73728;
  __hip_bfloat16* wtv2  = (__hip_bfloat16*)p; p += 73728;
  __hip_bfloat16* wtf1  = (__hip_bfloat16*)p; p += 393216;
  __hip_bfloat16* wtf2  = (__hip_bfloat16*)p; p += 393216;
  float* bkv1 = p; p += 768;
  float* peq  = p; p += (size_t)NN * DIM;
  float* pekv = p; p += (size_t)NN * DIM;
  int*   y0buf = (int*)p; p += (size_t)BB * NG * NKK * NN;
  float* wbuf  = p;
  float* res   = kvr;
  float* res2  = qproj;
  float* lnout = qrows;

  // 0) weight convert+transpose to bf16 + concat bias (graph-safe, every call)
  wtrans_kernel<<<dim3(DIM/32, DIM/32), dim3(32, 8), 0, stream>>>(Wq1, wtq1, DIM, DIM);
  wtrans_kernel<<<dim3(DIM/32, DIM/32), dim3(32, 8), 0, stream>>>(Wq2, wtq2, DIM, DIM);
  wtrans_kernel<<<dim3(DIM/32, DIM/32), dim3(32, 8), 0, stream>>>(Wk1, wtkv1, DIM, DIM);
  wtrans_kernel<<<dim3(DIM/32, DIM/32), dim3(32, 8), 0, stream>>>(
      Wv1, wtkv1 + (size_t)DIM * DIM, DIM, DIM);
  wtrans_kernel<<<dim3(DIM/32, DIM/32), dim3(32, 8), 0, stream>>>(Wk2, wtk2, DIM, DIM);
  wtrans_kernel<<<dim3(DIM/32, DIM/32), dim3(32, 8), 0, stream>>>(Wv2, wtv2, DIM, DIM);
  wtrans_kernel<<<dim3(DFF/32, DIM/32), dim3(32, 8), 0, stream>>>(Wf1, wtf1, DIM, DFF);
  wtrans_kernel<<<dim3(DIM/32, DFF/32), dim3(32, 8), 0, stream>>>(Wf2, wtf2, DFF, DIM);
  concat_bias_kernel<<<dim3(3), dim3(256), 0, stream>>>(bk1, bv1, bkv1, DIM);

  // 1) positional-encoding LayerNorms
  ln_rows_kernel<false><<<dim3(NN), dim3(128), 0, stream>>>(
      emb_q, ln_pq_g, ln_pq_b, peq, nullptr);
  ln_rows_kernel<false><<<dim3(NN), dim3(128), 0, stream>>>(
      emb_kv, ln_pkv_g, ln_pkv_b, pekv, nullptr);

  // 2) transpose to rows + add pos-enc (q also emits bf16 for the MLP)
  transpose_addpe<true><<<dim3(NN/32, DIM/32, BB), dim3(32, 8), 0, stream>>>(
      q_raw, peq, qrows, qrows_bf);
  transpose_addpe<false><<<dim3(NN/32, DIM/32, BB), dim3(32, 8), 0, stream>>>(
      kv_raw, pekv, kvr, nullptr);

  // 3) q MLP (bf16 MFMA; hidden bf16, output f32)
  mfma_gemm_kernel<true, false, true><<<dim3(DIM/128, MQ/128), 256, 0, stream>>>(
      qrows_bf, wtq1, bq1, nullptr, nullptr, scr_bf, DIM, DIM, DIM);
  mfma_gemm_kernel<false, false, false><<<dim3(DIM/128, MQ/128), 256, 0, stream>>>(
      scr_bf, wtq2, bq2, nullptr, qproj, nullptr, DIM, DIM, DIM);

  // 4) offset prediction -> sampling coords (f32, channel-per-lane, n-tiled)
  offset3_kernel<<<dim3(BB * NG, NN / 16), dim3(192), 0, stream>>>(
      qproj, dw_w, dw_b, pw_w, y0buf, wbuf);

  // 5) per batch-chunk: sample once, fused k1|v1 GEMM, merged k2|v2, attention
  for (int c = 0; c < NCH; ++c) {
    const int byBase = c * BY_PER_CH;
    sample_rows_kernel<<<dim3(ROWS_PER_CH * 3 / 16), 256, 0, stream>>>(
        kvr, y0buf, wbuf, sampA_bf, byBase);
    mfma_gemm_kernel<true, false, true><<<dim3(2*DIM/128, ROWS_PER_CH/128), 256, 0, stream>>>(
        sampA_bf, wtkv1, bkv1, nullptr, nullptr, hidkv_bf, DIM, 2*DIM, DIM);
    mfma_gemm_kv2<<<dim3(DIM/128, 2 * ROWS_PER_CH/128), 256, 0, stream>>>(
        hidkv_bf, wtk2, wtv2, bk2, bv2, k_ch, v_ch);
    attn_kernel<<<dim3(B_PER_CH * NN * NH), 128, 0, stream>>>(
        qproj, k_ch, v_ch, attn_scale, qrows, c * B_PER_CH);
  }

  // 6) res = LN(q_pe + attn_out); also emit bf16 for FFN input
  ln_rows_kernel<true><<<dim3(MQ), dim3(128), 0, stream>>>(
      qrows, ln1_g, ln1_b, res, res_bf);

  // 7) FFN in row-chunks (bf16 MFMA), residual fused into second GEMM
  for (int q = 0; q < NFQ; ++q) {
    const size_t roff = (size_t)q * FROWS;
    mfma_gemm_kernel<true, false, true><<<dim3(DFF/128, FROWS/128), 256, 0, stream>>>(
        res_bf + roff * DIM, wtf1, bf1, nullptr, nullptr, ffnh, DIM, DFF, DIM);
    mfma_gemm_kernel<false, true, false><<<dim3(DIM/128, FROWS/128), 256, 0, stream>>>(
        ffnh, wtf2, bf2, res + roff * DIM, res2 + roff * DIM, nullptr, DFF, DIM, DFF);
  }

  // 8) final LN + transpose back to (B, DIM, N)
  ln_rows_kernel<false><<<dim3(MQ), dim3(128), 0, stream>>>(
      res2, ln2_g, ln2_b, lnout, nullptr);
  transpose_to_cf<<<dim3(NN/32, DIM/32, BB), dim3(32, 8), 0, stream>>>(
      lnout, out);
}